// Round 8
// baseline (773.455 us; speedup 1.0000x reference)
//
#include <hip/hip_runtime.h>

constexpr int N = 50000;
constexpr int E = 800000;
constexpr int D = 128;
constexpr int MASKN = 25000;
constexpr int CAP = 96;   // bucket capacity; deg ~ Poisson(16), P(>96) ~ 0
constexpr int NPART = 64; // node ranges for atomic-free build
constexpr int RANGE = (N + NPART - 1) / NPART; // 782

typedef _Float16 half8 __attribute__((ext_vector_type(8)));
typedef _Float16 half4 __attribute__((ext_vector_type(4)));

#define DOT_STEP(w, a, acc)                                                    \
    acc = fmaf(w.x, a.x, acc);                                                 \
    acc = fmaf(w.y, a.y, acc);                                                 \
    acc = fmaf(w.z, a.z, acc);                                                 \
    acc = fmaf(w.w, a.w, acc)

#define ROW8(X) X(0) X(1) X(2) X(3) X(4) X(5) X(6) X(7)

// ---------------- atomic-free bucket build ----------------
// blocks [0,NPART): scan dst, own node range, LDS cursor -> col buckets + deg_in
// blocks [NPART,2*NPART): scan src, LDS histogram -> cnt_src (deg_out)

__launch_bounds__(256)
__global__ void k_build2(const int4* __restrict__ src4, const int4* __restrict__ dst4,
                         const int* __restrict__ src,
                         int* __restrict__ cnt_src, int* __restrict__ deg_in,
                         unsigned short* __restrict__ col) {
    __shared__ int cur[RANGE];
    int b = blockIdx.x, t = threadIdx.x;
    bool hist = b >= NPART;
    int p = hist ? b - NPART : b;
    int lo = p * RANGE;
    int hi = lo + RANGE < N ? lo + RANGE : N;
    for (int i = t; i < RANGE; i += 256) cur[i] = 0;
    __syncthreads();
    const int4* key4 = hist ? src4 : dst4;
    constexpr int NITER = E / 4; // 200000
    if (hist) {
        for (int i = t; i < NITER; i += 256) {
            int4 k = key4[i];
            if (k.x >= lo && k.x < hi) atomicAdd(&cur[k.x - lo], 1);
            if (k.y >= lo && k.y < hi) atomicAdd(&cur[k.y - lo], 1);
            if (k.z >= lo && k.z < hi) atomicAdd(&cur[k.z - lo], 1);
            if (k.w >= lo && k.w < hi) atomicAdd(&cur[k.w - lo], 1);
        }
    } else {
        for (int i = t; i < NITER; i += 256) {
            int4 k = key4[i];
#define BUILD_C(comp, off)                                                     \
            if (k.comp >= lo && k.comp < hi) {                                 \
                int s = src[4 * i + off];                                      \
                int pos = atomicAdd(&cur[k.comp - lo], 1);                     \
                col[(size_t)k.comp * CAP + pos] = (unsigned short)s;           \
            }
            BUILD_C(x, 0)
            BUILD_C(y, 1)
            BUILD_C(z, 2)
            BUILD_C(w, 3)
#undef BUILD_C
        }
    }
    __syncthreads();
    int* outp = hist ? cnt_src : deg_in;
    for (int i = t; lo + i < hi; i += 256) outp[lo + i] = cur[i];
}

// ---------------- fused setup: 4x W-transpose + dinv + mflag ----------------

__global__ void k_misc(const float4* __restrict__ W1, const float4* __restrict__ W2,
                       const float4* __restrict__ WE, const float4* __restrict__ WD,
                       float4* __restrict__ Wr1, float4* __restrict__ Wr2,
                       float4* __restrict__ WrE, float4* __restrict__ WrD,
                       const int* __restrict__ cs, const int* __restrict__ cd,
                       float* __restrict__ dinv_out, float* __restrict__ dinv_in,
                       const int* __restrict__ mask_nodes, int* __restrict__ mflag) {
    int b = blockIdx.x;
    if (b < 64) { // Wr[k4*128+o] = W[o*32+k4], 4 matrices x 16 blocks
        int m = b >> 4;
        int idx = (b & 15) * 256 + threadIdx.x;
        const float4* W = m == 0 ? W1 : m == 1 ? W2 : m == 2 ? WE : WD;
        float4* Wr = m == 0 ? Wr1 : m == 1 ? Wr2 : m == 2 ? WrE : WrD;
        int o = idx >> 5, k4 = idx & 31;
        Wr[k4 * 128 + o] = W[idx];
    } else if (b < 64 + 196) {
        int i = (b - 64) * 256 + threadIdx.x;
        if (i < N) {
            int a = cs[i] > 1 ? cs[i] : 1;
            int bb = cd[i] > 1 ? cd[i] : 1;
            dinv_out[i] = rsqrtf((float)a);
            dinv_in[i] = rsqrtf((float)bb);
        }
    } else {
        int i = (b - 260) * 256 + threadIdx.x;
        if (i < MASKN) mflag[mask_nodes[i]] = 1;
    }
}

// ---------------- feature prep: masked x scaled by deg_out^-0.5, fp16 out ----

__global__ void k_prep(const float4* __restrict__ x, const float4* __restrict__ tok,
                       const int* __restrict__ mflag, const float* __restrict__ dinv_out,
                       half4* __restrict__ Ah4) {
    int i = blockIdx.x * blockDim.x + threadIdx.x; // over N*32 float4s
    if (i < N * 32) {
        int row = i >> 5;
        int c = i & 31;
        float s = dinv_out[row];
        float4 v = mflag[row] ? tok[c] : x[i];
        half4 h;
        h[0] = (_Float16)(v.x * s);
        h[1] = (_Float16)(v.y * s);
        h[2] = (_Float16)(v.z * s);
        h[3] = (_Float16)(v.w * s);
        Ah4[i] = h;
    }
}

// ---------------- SpMM: B[row] = sum over bucket neighbors of Ah[col] ----------

__launch_bounds__(256)
__global__ void k_spmm(const half8* __restrict__ Ah8, float4* __restrict__ B4,
                       const int* __restrict__ deg, const unsigned short* __restrict__ col,
                       const int* __restrict__ rows, int nrows) {
    int wv = threadIdx.x >> 6, lane = threadIdx.x & 63;
    int q = lane >> 4, j = lane & 15;
    int rr = blockIdx.x * 4 + wv;
    if (rr >= nrows) return;
    int row = rows ? rows[rr] : rr;
    int dg = deg[row];
    const unsigned short* crow = col + (size_t)row * CAP;
    float a0 = 0.f, a1 = 0.f, a2 = 0.f, a3 = 0.f;
    float a4 = 0.f, a5 = 0.f, a6 = 0.f, a7 = 0.f;
    int e = q;
    for (; e + 4 < dg; e += 8) {
        int c0 = crow[e], c1 = crow[e + 4];
        half8 h0 = Ah8[(size_t)c0 * 16 + j];
        half8 h1 = Ah8[(size_t)c1 * 16 + j];
#define SP_ACC(i) a##i += (float)h0[i]; a##i += (float)h1[i];
        ROW8(SP_ACC)
#undef SP_ACC
    }
    if (e < dg) {
        int c0 = crow[e];
        half8 h0 = Ah8[(size_t)c0 * 16 + j];
#define SP_ACC1(i) a##i += (float)h0[i];
        ROW8(SP_ACC1)
#undef SP_ACC1
    }
#pragma unroll
    for (int o = 16; o <= 32; o <<= 1) {
#define SP_SHFL(i) a##i += __shfl_xor(a##i, o);
        ROW8(SP_SHFL)
#undef SP_SHFL
    }
    if (q == 0) {
        B4[(size_t)row * 32 + j * 2] = make_float4(a0, a1, a2, a3);
        B4[(size_t)row * 32 + j * 2 + 1] = make_float4(a4, a5, a6, a7);
    }
}

// ---------------- dense: thread t = output col, 8 rows/block, coalesced Wr ----

template <bool LN, bool SCALE_OUT, bool MASK_ZERO, bool OUT_HALF>
__launch_bounds__(128)
__global__ void k_dense(const float* __restrict__ in, float* __restrict__ out,
                        _Float16* __restrict__ outh,
                        const float4* __restrict__ Wr4, const float* __restrict__ bias,
                        const float* __restrict__ g, const float* __restrict__ be,
                        const float* __restrict__ aP, const float* __restrict__ dinv_in,
                        const float* __restrict__ dinv_out, const int* __restrict__ mflag) {
    __shared__ float sh[8 * 128];
    __shared__ float red[32];
    int t = threadIdx.x;
    int r0 = blockIdx.x * 8; // N % 8 == 0
    {
        const float4* inb = (const float4*)(in + (size_t)r0 * 128);
        float4* s4 = (float4*)sh;
        s4[t] = inb[t];
        s4[t + 128] = inb[t + 128];
    }
    __syncthreads();
    const float4* sh4 = (const float4*)sh;
    float acc0 = 0.f, acc1 = 0.f, acc2 = 0.f, acc3 = 0.f;
    float acc4 = 0.f, acc5 = 0.f, acc6 = 0.f, acc7 = 0.f;
#pragma unroll 2
    for (int k4 = 0; k4 < 32; ++k4) {
        float4 w = Wr4[k4 * 128 + t];
#define DENSE_FMA(i)                                                           \
        {                                                                      \
            float4 a = sh4[i * 32 + k4];                                       \
            DOT_STEP(w, a, acc##i);                                            \
        }
        ROW8(DENSE_FMA)
#undef DENSE_FMA
    }
#define V_DECL(i) float v##i = acc##i;
    ROW8(V_DECL)
#undef V_DECL
    if constexpr (LN) {
        float bt = bias[t];
#define LN_PRE(i) v##i = (v##i + bt) * dinv_in[r0 + i];
        ROW8(LN_PRE)
#undef LN_PRE
#define LN_DECL(i) float s##i = v##i, q##i = v##i * v##i;
        ROW8(LN_DECL)
#undef LN_DECL
#pragma unroll
        for (int o = 32; o > 0; o >>= 1) {
#define LN_SHFL(i)                                                             \
            s##i += __shfl_xor(s##i, o);                                       \
            q##i += __shfl_xor(q##i, o);
            ROW8(LN_SHFL)
#undef LN_SHFL
        }
        if ((t & 63) == 0) {
            int wv = t >> 6;
#define LN_RED(i)                                                              \
            red[wv * 16 + 2 * i] = s##i;                                       \
            red[wv * 16 + 2 * i + 1] = q##i;
            ROW8(LN_RED)
#undef LN_RED
        }
        __syncthreads();
        float gt = g[t], bet = be[t], alpha = aP[0];
#define LN_ROW(i)                                                              \
        {                                                                      \
            float S = red[2 * i] + red[16 + 2 * i];                            \
            float Q = red[2 * i + 1] + red[16 + 2 * i + 1];                    \
            float mu = S * (1.f / D);                                          \
            float var = Q * (1.f / D) - mu * mu;                               \
            float rs = rsqrtf(var + 1e-5f);                                    \
            v##i = (v##i - mu) * rs * gt + bet;                                \
            v##i = v##i >= 0.f ? v##i : alpha * v##i;                          \
        }
        ROW8(LN_ROW)
#undef LN_ROW
    }
    if constexpr (MASK_ZERO) {
#define MZ(i) if (mflag[r0 + i]) v##i = 0.f;
        ROW8(MZ)
#undef MZ
    }
    if constexpr (SCALE_OUT) {
#define SO(i) v##i *= dinv_out[r0 + i];
        ROW8(SO)
#undef SO
    }
    if constexpr (OUT_HALF) {
#define STOREH(i) outh[(size_t)(r0 + i) * 128 + t] = (_Float16)v##i;
        ROW8(STOREH)
#undef STOREH
    } else {
#define STORE(i) out[(size_t)(r0 + i) * 128 + t] = v##i;
        ROW8(STORE)
#undef STORE
    }
}

// ---------------- fused conv2-epilogue + encoder_to_decoder ----------------
// phase A: h2 = PReLU(LN((agg2 + b2) * dinv_in)) kept in LDS
// phase B: rep = h2 @ We2d^T, re-mask, * dinv_out, -> fp16 Ah

__launch_bounds__(128)
__global__ void k_dense23(const float* __restrict__ in, _Float16* __restrict__ outh,
                          const float4* __restrict__ Wr2, const float4* __restrict__ WrE,
                          const float* __restrict__ bias, const float* __restrict__ g,
                          const float* __restrict__ be, const float* __restrict__ aP,
                          const float* __restrict__ dinv_in, const float* __restrict__ dinv_out,
                          const int* __restrict__ mflag) {
    __shared__ float sh[8 * 128];
    __shared__ float red[32];
    int t = threadIdx.x;
    int r0 = blockIdx.x * 8;
    {
        const float4* inb = (const float4*)(in + (size_t)r0 * 128);
        float4* s4 = (float4*)sh;
        s4[t] = inb[t];
        s4[t + 128] = inb[t + 128];
    }
    __syncthreads();
    const float4* sh4 = (const float4*)sh;
    float acc0 = 0.f, acc1 = 0.f, acc2 = 0.f, acc3 = 0.f;
    float acc4 = 0.f, acc5 = 0.f, acc6 = 0.f, acc7 = 0.f;
#pragma unroll 2
    for (int k4 = 0; k4 < 32; ++k4) {
        float4 w = Wr2[k4 * 128 + t];
#define DENSE_FMA(i)                                                           \
        {                                                                      \
            float4 a = sh4[i * 32 + k4];                                       \
            DOT_STEP(w, a, acc##i);                                            \
        }
        ROW8(DENSE_FMA)
#undef DENSE_FMA
    }
#define V_DECL(i) float v##i = acc##i;
    ROW8(V_DECL)
#undef V_DECL
    {
        float bt = bias[t];
#define LN_PRE(i) v##i = (v##i + bt) * dinv_in[r0 + i];
        ROW8(LN_PRE)
#undef LN_PRE
#define LN_DECL(i) float s##i = v##i, q##i = v##i * v##i;
        ROW8(LN_DECL)
#undef LN_DECL
#pragma unroll
        for (int o = 32; o > 0; o >>= 1) {
#define LN_SHFL(i)                                                             \
            s##i += __shfl_xor(s##i, o);                                       \
            q##i += __shfl_xor(q##i, o);
            ROW8(LN_SHFL)
#undef LN_SHFL
        }
        if ((t & 63) == 0) {
            int wv = t >> 6;
#define LN_RED(i)                                                              \
            red[wv * 16 + 2 * i] = s##i;                                       \
            red[wv * 16 + 2 * i + 1] = q##i;
            ROW8(LN_RED)
#undef LN_RED
        }
        __syncthreads();
        float gt = g[t], bet = be[t], alpha = aP[0];
#define LN_ROW(i)                                                              \
        {                                                                      \
            float S = red[2 * i] + red[16 + 2 * i];                            \
            float Q = red[2 * i + 1] + red[16 + 2 * i + 1];                    \
            float mu = S * (1.f / D);                                          \
            float var = Q * (1.f / D) - mu * mu;                               \
            float rs = rsqrtf(var + 1e-5f);                                    \
            v##i = (v##i - mu) * rs * gt + bet;                                \
            v##i = v##i >= 0.f ? v##i : alpha * v##i;                          \
        }
        ROW8(LN_ROW)
#undef LN_ROW
    }
    // phase B: h2 -> LDS, then rep = h2 @ We2d^T
    __syncthreads();
#define H2ST(i) sh[i * 128 + t] = v##i;
    ROW8(H2ST)
#undef H2ST
    __syncthreads();
    acc0 = 0.f; acc1 = 0.f; acc2 = 0.f; acc3 = 0.f;
    acc4 = 0.f; acc5 = 0.f; acc6 = 0.f; acc7 = 0.f;
#pragma unroll 2
    for (int k4 = 0; k4 < 32; ++k4) {
        float4 w = WrE[k4 * 128 + t];
#define DENSE_FMA(i)                                                           \
        {                                                                      \
            float4 a = sh4[i * 32 + k4];                                       \
            DOT_STEP(w, a, acc##i);                                            \
        }
        ROW8(DENSE_FMA)
#undef DENSE_FMA
    }
#define REP_EPI(i)                                                             \
    {                                                                          \
        float vv = mflag[r0 + i] ? 0.f : acc##i * dinv_out[r0 + i];            \
        outh[(size_t)(r0 + i) * 128 + t] = (_Float16)vv;                       \
    }
    ROW8(REP_EPI)
#undef REP_EPI
}

// decoder fc + degnorm + SCE loss over masked rows (8 rows/block)
__launch_bounds__(128)
__global__ void k_loss(const float* __restrict__ agg, const float* __restrict__ x,
                       const float4* __restrict__ Wr4, const float* __restrict__ bd,
                       const float* __restrict__ dinv_in, const int* __restrict__ mask_nodes,
                       float* __restrict__ outp) {
    __shared__ float sh[8 * 128];
    __shared__ float red[48];
    __shared__ int shm[8];
    int t = threadIdx.x;
    int i0 = blockIdx.x * 8; // MASKN % 8 == 0
    if (t < 8) shm[t] = mask_nodes[i0 + t];
    __syncthreads();
#pragma unroll
    for (int i = 0; i < 8; ++i) sh[i * 128 + t] = agg[(size_t)shm[i] * 128 + t];
    __syncthreads();
    const float4* sh4 = (const float4*)sh;
    float acc0 = 0.f, acc1 = 0.f, acc2 = 0.f, acc3 = 0.f;
    float acc4 = 0.f, acc5 = 0.f, acc6 = 0.f, acc7 = 0.f;
#pragma unroll 2
    for (int k4 = 0; k4 < 32; ++k4) {
        float4 w = Wr4[k4 * 128 + t];
#define LOSS_FMA(i)                                                            \
        {                                                                      \
            float4 a = sh4[i * 32 + k4];                                       \
            DOT_STEP(w, a, acc##i);                                            \
        }
        ROW8(LOSS_FMA)
#undef LOSS_FMA
    }
    float bt = bd[t];
#define LOSS_RXC(i)                                                            \
    float r##i = (acc##i + bt) * dinv_in[shm[i]];                              \
    float xv##i = x[(size_t)shm[i] * 128 + t];                                 \
    float a##i = r##i * r##i, b##i = xv##i * xv##i, c##i = r##i * xv##i;
    ROW8(LOSS_RXC)
#undef LOSS_RXC
#pragma unroll
    for (int o = 32; o > 0; o >>= 1) {
#define LOSS_SHFL(i)                                                           \
        a##i += __shfl_xor(a##i, o);                                           \
        b##i += __shfl_xor(b##i, o);                                           \
        c##i += __shfl_xor(c##i, o);
        ROW8(LOSS_SHFL)
#undef LOSS_SHFL
    }
    if ((t & 63) == 0) {
        int wv = t >> 6;
#define LOSS_RED(i)                                                            \
        red[wv * 24 + 3 * i] = a##i;                                           \
        red[wv * 24 + 3 * i + 1] = b##i;                                       \
        red[wv * 24 + 3 * i + 2] = c##i;
        ROW8(LOSS_RED)
#undef LOSS_RED
    }
    __syncthreads();
    if (t == 0) {
        float sum = 0.f;
#pragma unroll
        for (int i = 0; i < 8; ++i) {
            float A_ = red[3 * i] + red[24 + 3 * i];
            float B_ = red[3 * i + 1] + red[24 + 3 * i + 1];
            float C_ = red[3 * i + 2] + red[24 + 3 * i + 2];
            float nr = fmaxf(sqrtf(A_), 1e-12f);
            float nx = fmaxf(sqrtf(B_), 1e-12f);
            float term = 1.f - C_ / (nr * nx);
            sum += term * term;
        }
        atomicAdd(outp, sum * (1.f / MASKN));
    }
}

// ---------------- launch ----------------

extern "C" void kernel_launch(void* const* d_in, const int* in_sizes, int n_in,
                              void* d_out, int out_size, void* d_ws, size_t ws_size,
                              hipStream_t stream) {
    const float* x = (const float*)d_in[0];
    const float* tok = (const float*)d_in[1];
    const float* W1 = (const float*)d_in[2];
    const float* b1 = (const float*)d_in[3];
    const float* g1 = (const float*)d_in[4];
    const float* be1 = (const float*)d_in[5];
    const float* a1 = (const float*)d_in[6];
    const float* W2 = (const float*)d_in[7];
    const float* b2 = (const float*)d_in[8];
    const float* g2 = (const float*)d_in[9];
    const float* be2 = (const float*)d_in[10];
    const float* a2 = (const float*)d_in[11];
    const float* We2d = (const float*)d_in[12];
    const float* Wd = (const float*)d_in[13];
    const float* bd = (const float*)d_in[14];
    const int* src = (const int*)d_in[15];
    const int* dst = (const int*)d_in[16];
    const int* mask_nodes = (const int*)d_in[17];

    char* w = (char*)d_ws;
    _Float16* Ah = (_Float16*)w;        w += (size_t)N * D * 2;
    float* Bf = (float*)w;              w += (size_t)N * D * 4;
    unsigned short* col = (unsigned short*)w; w += (size_t)N * CAP * 2;
    int* cnt_src = (int*)w;             w += (size_t)N * 4;
    int* deg_in = (int*)w;              w += (size_t)N * 4;
    int* mflag = (int*)w;               w += (size_t)N * 4;
    float* dinv_out = (float*)w;        w += (size_t)N * 4;
    float* dinv_in = (float*)w;         w += (size_t)N * 4;
    float* Wr1 = (float*)w;             w += (size_t)D * D * 4;
    float* Wr2 = (float*)w;             w += (size_t)D * D * 4;
    float* WrE = (float*)w;             w += (size_t)D * D * 4;
    float* WrD = (float*)w;             w += (size_t)D * D * 4;

    // zero mflag + output scalar (cnt_src/deg_in/col fully written by k_build2)
    hipMemsetAsync(mflag, 0, (size_t)N * 4, stream);
    hipMemsetAsync(d_out, 0, sizeof(float), stream);

    k_build2<<<2 * NPART, 256, 0, stream>>>((const int4*)src, (const int4*)dst, src,
                                            cnt_src, deg_in, col);
    k_misc<<<358, 256, 0, stream>>>(
        (const float4*)W1, (const float4*)W2, (const float4*)We2d, (const float4*)Wd,
        (float4*)Wr1, (float4*)Wr2, (float4*)WrE, (float4*)WrD,
        cnt_src, deg_in, dinv_out, dinv_in, mask_nodes, mflag);
    k_prep<<<(N * 32 + 255) / 256, 256, 0, stream>>>((const float4*)x, (const float4*)tok,
                                                     mflag, dinv_out, (half4*)Ah);
    int ndense = N / 8;     // 6250
    int nloss = MASKN / 8;  // 3125
    int nspmm = (N + 3) / 4;
    // conv1: agg (fp16 gather)
    k_spmm<<<nspmm, 256, 0, stream>>>((const half8*)Ah, (float4*)Bf, deg_in, col, nullptr, N);
    // conv1 epilogue -> fp16, pre-scaled by deg_out^-0.5
    k_dense<true, true, false, true><<<ndense, 128, 0, stream>>>(
        Bf, nullptr, Ah, (const float4*)Wr1, b1, g1, be1, a1, dinv_in, dinv_out, nullptr);
    // conv2: agg
    k_spmm<<<nspmm, 256, 0, stream>>>((const half8*)Ah, (float4*)Bf, deg_in, col, nullptr, N);
    // conv2 epilogue + encoder_to_decoder + re-mask + pre-scale -> fp16 (fused)
    k_dense23<<<ndense, 128, 0, stream>>>(
        Bf, Ah, (const float4*)Wr2, (const float4*)WrE, b2, g2, be2, a2,
        dinv_in, dinv_out, mflag);
    // conv3: agg, masked rows only
    k_spmm<<<(MASKN + 3) / 4, 256, 0, stream>>>((const half8*)Ah, (float4*)Bf, deg_in, col,
                                                mask_nodes, MASKN);
    // decoder fc + SCE loss
    k_loss<<<nloss, 128, 0, stream>>>(Bf, x, (const float4*)WrD, bd,
                                      dinv_in, mask_nodes, (float*)d_out);
}

// Round 9
// 442.608 us; speedup vs baseline: 1.7475x; 1.7475x over previous
//
#include <hip/hip_runtime.h>

constexpr int N = 50000;
constexpr int E = 800000;
constexpr int D = 128;
constexpr int MASKN = 25000;
constexpr int CAP = 96; // bucket capacity; deg ~ Poisson(16), P(>96) ~ 0

typedef _Float16 half8 __attribute__((ext_vector_type(8)));
typedef _Float16 half4 __attribute__((ext_vector_type(4)));

#define DOT_STEP(w, a, acc)                                                    \
    acc = fmaf(w.x, a.x, acc);                                                 \
    acc = fmaf(w.y, a.y, acc);                                                 \
    acc = fmaf(w.z, a.z, acc);                                                 \
    acc = fmaf(w.w, a.w, acc)

#define ROW8(X) X(0) X(1) X(2) X(3) X(4) X(5) X(6) X(7)

// ---------------- one-pass bucket build (device atomics — measured 77us,
// beats every atomic-free scheme tried; see R8 post-mortem) ----------------

__global__ void k_build(const int* __restrict__ src, const int* __restrict__ dst,
                        int* __restrict__ cnt_src, int* __restrict__ cursor,
                        unsigned short* __restrict__ col) {
    int e = blockIdx.x * blockDim.x + threadIdx.x;
    if (e < E) {
        int s = src[e], d = dst[e];
        atomicAdd(&cnt_src[s], 1);
        int p = atomicAdd(&cursor[d], 1);
        col[(size_t)d * CAP + p] = (unsigned short)s;
    }
}

// ---------------- fused setup: 4x W-transpose + dinv + mflag ----------------

__global__ void k_misc(const float4* __restrict__ W1, const float4* __restrict__ W2,
                       const float4* __restrict__ WE, const float4* __restrict__ WD,
                       float4* __restrict__ Wr1, float4* __restrict__ Wr2,
                       float4* __restrict__ WrE, float4* __restrict__ WrD,
                       const int* __restrict__ cs, const int* __restrict__ cd,
                       float* __restrict__ dinv_out, float* __restrict__ dinv_in,
                       const int* __restrict__ mask_nodes, int* __restrict__ mflag) {
    int b = blockIdx.x;
    if (b < 64) { // Wr[k4*128+o] = W[o*32+k4], 4 matrices x 16 blocks
        int m = b >> 4;
        int idx = (b & 15) * 256 + threadIdx.x;
        const float4* W = m == 0 ? W1 : m == 1 ? W2 : m == 2 ? WE : WD;
        float4* Wr = m == 0 ? Wr1 : m == 1 ? Wr2 : m == 2 ? WrE : WrD;
        int o = idx >> 5, k4 = idx & 31;
        Wr[k4 * 128 + o] = W[idx];
    } else if (b < 64 + 196) {
        int i = (b - 64) * 256 + threadIdx.x;
        if (i < N) {
            int a = cs[i] > 1 ? cs[i] : 1;
            int bb = cd[i] > 1 ? cd[i] : 1;
            dinv_out[i] = rsqrtf((float)a);
            dinv_in[i] = rsqrtf((float)bb);
        }
    } else {
        int i = (b - 260) * 256 + threadIdx.x;
        if (i < MASKN) mflag[mask_nodes[i]] = 1;
    }
}

// ---------------- feature prep: masked x scaled by deg_out^-0.5, fp16 out ----

__global__ void k_prep(const float4* __restrict__ x, const float4* __restrict__ tok,
                       const int* __restrict__ mflag, const float* __restrict__ dinv_out,
                       half4* __restrict__ Ah4) {
    int i = blockIdx.x * blockDim.x + threadIdx.x; // over N*32 float4s
    if (i < N * 32) {
        int row = i >> 5;
        int c = i & 31;
        float s = dinv_out[row];
        float4 v = mflag[row] ? tok[c] : x[i];
        half4 h;
        h[0] = (_Float16)(v.x * s);
        h[1] = (_Float16)(v.y * s);
        h[2] = (_Float16)(v.z * s);
        h[3] = (_Float16)(v.w * s);
        Ah4[i] = h;
    }
}

// ---------------- SpMM: B[row] = sum over bucket neighbors of Ah[col] ----------

__launch_bounds__(256)
__global__ void k_spmm(const half8* __restrict__ Ah8, float4* __restrict__ B4,
                       const int* __restrict__ deg, const unsigned short* __restrict__ col,
                       const int* __restrict__ rows, int nrows) {
    int wv = threadIdx.x >> 6, lane = threadIdx.x & 63;
    int q = lane >> 4, j = lane & 15;
    int rr = blockIdx.x * 4 + wv;
    if (rr >= nrows) return;
    int row = rows ? rows[rr] : rr;
    int dg = deg[row];
    const unsigned short* crow = col + (size_t)row * CAP;
    float a0 = 0.f, a1 = 0.f, a2 = 0.f, a3 = 0.f;
    float a4 = 0.f, a5 = 0.f, a6 = 0.f, a7 = 0.f;
    int e = q;
    for (; e + 4 < dg; e += 8) {
        int c0 = crow[e], c1 = crow[e + 4];
        half8 h0 = Ah8[(size_t)c0 * 16 + j];
        half8 h1 = Ah8[(size_t)c1 * 16 + j];
#define SP_ACC(i) a##i += (float)h0[i]; a##i += (float)h1[i];
        ROW8(SP_ACC)
#undef SP_ACC
    }
    if (e < dg) {
        int c0 = crow[e];
        half8 h0 = Ah8[(size_t)c0 * 16 + j];
#define SP_ACC1(i) a##i += (float)h0[i];
        ROW8(SP_ACC1)
#undef SP_ACC1
    }
#pragma unroll
    for (int o = 16; o <= 32; o <<= 1) {
#define SP_SHFL(i) a##i += __shfl_xor(a##i, o);
        ROW8(SP_SHFL)
#undef SP_SHFL
    }
    if (q == 0) {
        B4[(size_t)row * 32 + j * 2] = make_float4(a0, a1, a2, a3);
        B4[(size_t)row * 32 + j * 2 + 1] = make_float4(a4, a5, a6, a7);
    }
}

// ---------------- dense: thread t = output col, 8 rows/block, coalesced Wr ----

template <bool LN, bool SCALE_OUT, bool MASK_ZERO, bool OUT_HALF>
__launch_bounds__(128)
__global__ void k_dense(const float* __restrict__ in, float* __restrict__ out,
                        _Float16* __restrict__ outh,
                        const float4* __restrict__ Wr4, const float* __restrict__ bias,
                        const float* __restrict__ g, const float* __restrict__ be,
                        const float* __restrict__ aP, const float* __restrict__ dinv_in,
                        const float* __restrict__ dinv_out, const int* __restrict__ mflag) {
    __shared__ float sh[8 * 128];
    __shared__ float red[32];
    int t = threadIdx.x;
    int r0 = blockIdx.x * 8; // N % 8 == 0
    {
        const float4* inb = (const float4*)(in + (size_t)r0 * 128);
        float4* s4 = (float4*)sh;
        s4[t] = inb[t];
        s4[t + 128] = inb[t + 128];
    }
    __syncthreads();
    const float4* sh4 = (const float4*)sh;
    float acc0 = 0.f, acc1 = 0.f, acc2 = 0.f, acc3 = 0.f;
    float acc4 = 0.f, acc5 = 0.f, acc6 = 0.f, acc7 = 0.f;
#pragma unroll 2
    for (int k4 = 0; k4 < 32; ++k4) {
        float4 w = Wr4[k4 * 128 + t];
#define DENSE_FMA(i)                                                           \
        {                                                                      \
            float4 a = sh4[i * 32 + k4];                                       \
            DOT_STEP(w, a, acc##i);                                            \
        }
        ROW8(DENSE_FMA)
#undef DENSE_FMA
    }
#define V_DECL(i) float v##i = acc##i;
    ROW8(V_DECL)
#undef V_DECL
    if constexpr (LN) {
        float bt = bias[t];
#define LN_PRE(i) v##i = (v##i + bt) * dinv_in[r0 + i];
        ROW8(LN_PRE)
#undef LN_PRE
#define LN_DECL(i) float s##i = v##i, q##i = v##i * v##i;
        ROW8(LN_DECL)
#undef LN_DECL
#pragma unroll
        for (int o = 32; o > 0; o >>= 1) {
#define LN_SHFL(i)                                                             \
            s##i += __shfl_xor(s##i, o);                                       \
            q##i += __shfl_xor(q##i, o);
            ROW8(LN_SHFL)
#undef LN_SHFL
        }
        if ((t & 63) == 0) {
            int wv = t >> 6;
#define LN_RED(i)                                                              \
            red[wv * 16 + 2 * i] = s##i;                                       \
            red[wv * 16 + 2 * i + 1] = q##i;
            ROW8(LN_RED)
#undef LN_RED
        }
        __syncthreads();
        float gt = g[t], bet = be[t], alpha = aP[0];
#define LN_ROW(i)                                                              \
        {                                                                      \
            float S = red[2 * i] + red[16 + 2 * i];                            \
            float Q = red[2 * i + 1] + red[16 + 2 * i + 1];                    \
            float mu = S * (1.f / D);                                          \
            float var = Q * (1.f / D) - mu * mu;                               \
            float rs = rsqrtf(var + 1e-5f);                                    \
            v##i = (v##i - mu) * rs * gt + bet;                                \
            v##i = v##i >= 0.f ? v##i : alpha * v##i;                          \
        }
        ROW8(LN_ROW)
#undef LN_ROW
    }
    if constexpr (MASK_ZERO) {
#define MZ(i) if (mflag[r0 + i]) v##i = 0.f;
        ROW8(MZ)
#undef MZ
    }
    if constexpr (SCALE_OUT) {
#define SO(i) v##i *= dinv_out[r0 + i];
        ROW8(SO)
#undef SO
    }
    if constexpr (OUT_HALF) {
#define STOREH(i) outh[(size_t)(r0 + i) * 128 + t] = (_Float16)v##i;
        ROW8(STOREH)
#undef STOREH
    } else {
#define STORE(i) out[(size_t)(r0 + i) * 128 + t] = v##i;
        ROW8(STORE)
#undef STORE
    }
}

// ---------------- fused conv2-epilogue + encoder_to_decoder ----------------
// phase A: h2 = PReLU(LN((agg2 + b2) * dinv_in)) kept in LDS
// phase B: rep = h2 @ We2d^T, re-mask, * dinv_out, -> fp16 Ah

__launch_bounds__(128)
__global__ void k_dense23(const float* __restrict__ in, _Float16* __restrict__ outh,
                          const float4* __restrict__ Wr2, const float4* __restrict__ WrE,
                          const float* __restrict__ bias, const float* __restrict__ g,
                          const float* __restrict__ be, const float* __restrict__ aP,
                          const float* __restrict__ dinv_in, const float* __restrict__ dinv_out,
                          const int* __restrict__ mflag) {
    __shared__ float sh[8 * 128];
    __shared__ float red[32];
    int t = threadIdx.x;
    int r0 = blockIdx.x * 8;
    {
        const float4* inb = (const float4*)(in + (size_t)r0 * 128);
        float4* s4 = (float4*)sh;
        s4[t] = inb[t];
        s4[t + 128] = inb[t + 128];
    }
    __syncthreads();
    const float4* sh4 = (const float4*)sh;
    float acc0 = 0.f, acc1 = 0.f, acc2 = 0.f, acc3 = 0.f;
    float acc4 = 0.f, acc5 = 0.f, acc6 = 0.f, acc7 = 0.f;
#pragma unroll 2
    for (int k4 = 0; k4 < 32; ++k4) {
        float4 w = Wr2[k4 * 128 + t];
#define DENSE_FMA(i)                                                           \
        {                                                                      \
            float4 a = sh4[i * 32 + k4];                                       \
            DOT_STEP(w, a, acc##i);                                            \
        }
        ROW8(DENSE_FMA)
#undef DENSE_FMA
    }
#define V_DECL(i) float v##i = acc##i;
    ROW8(V_DECL)
#undef V_DECL
    {
        float bt = bias[t];
#define LN_PRE(i) v##i = (v##i + bt) * dinv_in[r0 + i];
        ROW8(LN_PRE)
#undef LN_PRE
#define LN_DECL(i) float s##i = v##i, q##i = v##i * v##i;
        ROW8(LN_DECL)
#undef LN_DECL
#pragma unroll
        for (int o = 32; o > 0; o >>= 1) {
#define LN_SHFL(i)                                                             \
            s##i += __shfl_xor(s##i, o);                                       \
            q##i += __shfl_xor(q##i, o);
            ROW8(LN_SHFL)
#undef LN_SHFL
        }
        if ((t & 63) == 0) {
            int wv = t >> 6;
#define LN_RED(i)                                                              \
            red[wv * 16 + 2 * i] = s##i;                                       \
            red[wv * 16 + 2 * i + 1] = q##i;
            ROW8(LN_RED)
#undef LN_RED
        }
        __syncthreads();
        float gt = g[t], bet = be[t], alpha = aP[0];
#define LN_ROW(i)                                                              \
        {                                                                      \
            float S = red[2 * i] + red[16 + 2 * i];                            \
            float Q = red[2 * i + 1] + red[16 + 2 * i + 1];                    \
            float mu = S * (1.f / D);                                          \
            float var = Q * (1.f / D) - mu * mu;                               \
            float rs = rsqrtf(var + 1e-5f);                                    \
            v##i = (v##i - mu) * rs * gt + bet;                                \
            v##i = v##i >= 0.f ? v##i : alpha * v##i;                          \
        }
        ROW8(LN_ROW)
#undef LN_ROW
    }
    // phase B: h2 -> LDS, then rep = h2 @ We2d^T
    __syncthreads();
#define H2ST(i) sh[i * 128 + t] = v##i;
    ROW8(H2ST)
#undef H2ST
    __syncthreads();
    acc0 = 0.f; acc1 = 0.f; acc2 = 0.f; acc3 = 0.f;
    acc4 = 0.f; acc5 = 0.f; acc6 = 0.f; acc7 = 0.f;
#pragma unroll 2
    for (int k4 = 0; k4 < 32; ++k4) {
        float4 w = WrE[k4 * 128 + t];
#define DENSE_FMA(i)                                                           \
        {                                                                      \
            float4 a = sh4[i * 32 + k4];                                       \
            DOT_STEP(w, a, acc##i);                                            \
        }
        ROW8(DENSE_FMA)
#undef DENSE_FMA
    }
#define REP_EPI(i)                                                             \
    {                                                                          \
        float vv = mflag[r0 + i] ? 0.f : acc##i * dinv_out[r0 + i];            \
        outh[(size_t)(r0 + i) * 128 + t] = (_Float16)vv;                       \
    }
    ROW8(REP_EPI)
#undef REP_EPI
}

// decoder fc + degnorm + SCE loss over masked rows (8 rows/block)
__launch_bounds__(128)
__global__ void k_loss(const float* __restrict__ agg, const float* __restrict__ x,
                       const float4* __restrict__ Wr4, const float* __restrict__ bd,
                       const float* __restrict__ dinv_in, const int* __restrict__ mask_nodes,
                       float* __restrict__ outp) {
    __shared__ float sh[8 * 128];
    __shared__ float red[48];
    __shared__ int shm[8];
    int t = threadIdx.x;
    int i0 = blockIdx.x * 8; // MASKN % 8 == 0
    if (t < 8) shm[t] = mask_nodes[i0 + t];
    __syncthreads();
#pragma unroll
    for (int i = 0; i < 8; ++i) sh[i * 128 + t] = agg[(size_t)shm[i] * 128 + t];
    __syncthreads();
    const float4* sh4 = (const float4*)sh;
    float acc0 = 0.f, acc1 = 0.f, acc2 = 0.f, acc3 = 0.f;
    float acc4 = 0.f, acc5 = 0.f, acc6 = 0.f, acc7 = 0.f;
#pragma unroll 2
    for (int k4 = 0; k4 < 32; ++k4) {
        float4 w = Wr4[k4 * 128 + t];
#define LOSS_FMA(i)                                                            \
        {                                                                      \
            float4 a = sh4[i * 32 + k4];                                       \
            DOT_STEP(w, a, acc##i);                                            \
        }
        ROW8(LOSS_FMA)
#undef LOSS_FMA
    }
    float bt = bd[t];
#define LOSS_RXC(i)                                                            \
    float r##i = (acc##i + bt) * dinv_in[shm[i]];                              \
    float xv##i = x[(size_t)shm[i] * 128 + t];                                 \
    float a##i = r##i * r##i, b##i = xv##i * xv##i, c##i = r##i * xv##i;
    ROW8(LOSS_RXC)
#undef LOSS_RXC
#pragma unroll
    for (int o = 32; o > 0; o >>= 1) {
#define LOSS_SHFL(i)                                                           \
        a##i += __shfl_xor(a##i, o);                                           \
        b##i += __shfl_xor(b##i, o);                                           \
        c##i += __shfl_xor(c##i, o);
        ROW8(LOSS_SHFL)
#undef LOSS_SHFL
    }
    if ((t & 63) == 0) {
        int wv = t >> 6;
#define LOSS_RED(i)                                                            \
        red[wv * 24 + 3 * i] = a##i;                                           \
        red[wv * 24 + 3 * i + 1] = b##i;                                       \
        red[wv * 24 + 3 * i + 2] = c##i;
        ROW8(LOSS_RED)
#undef LOSS_RED
    }
    __syncthreads();
    if (t == 0) {
        float sum = 0.f;
#pragma unroll
        for (int i = 0; i < 8; ++i) {
            float A_ = red[3 * i] + red[24 + 3 * i];
            float B_ = red[3 * i + 1] + red[24 + 3 * i + 1];
            float C_ = red[3 * i + 2] + red[24 + 3 * i + 2];
            float nr = fmaxf(sqrtf(A_), 1e-12f);
            float nx = fmaxf(sqrtf(B_), 1e-12f);
            float term = 1.f - C_ / (nr * nx);
            sum += term * term;
        }
        atomicAdd(outp, sum * (1.f / MASKN));
    }
}

// ---------------- launch ----------------

extern "C" void kernel_launch(void* const* d_in, const int* in_sizes, int n_in,
                              void* d_out, int out_size, void* d_ws, size_t ws_size,
                              hipStream_t stream) {
    const float* x = (const float*)d_in[0];
    const float* tok = (const float*)d_in[1];
    const float* W1 = (const float*)d_in[2];
    const float* b1 = (const float*)d_in[3];
    const float* g1 = (const float*)d_in[4];
    const float* be1 = (const float*)d_in[5];
    const float* a1 = (const float*)d_in[6];
    const float* W2 = (const float*)d_in[7];
    const float* b2 = (const float*)d_in[8];
    const float* g2 = (const float*)d_in[9];
    const float* be2 = (const float*)d_in[10];
    const float* a2 = (const float*)d_in[11];
    const float* We2d = (const float*)d_in[12];
    const float* Wd = (const float*)d_in[13];
    const float* bd = (const float*)d_in[14];
    const int* src = (const int*)d_in[15];
    const int* dst = (const int*)d_in[16];
    const int* mask_nodes = (const int*)d_in[17];

    char* w = (char*)d_ws;
    _Float16* Ah = (_Float16*)w;        w += (size_t)N * D * 2;
    float* Bf = (float*)w;              w += (size_t)N * D * 4;
    unsigned short* col = (unsigned short*)w; w += (size_t)N * CAP * 2;
    int* cnt_src = (int*)w;             w += (size_t)N * 4;
    int* cursor = (int*)w;              w += (size_t)N * 4; // becomes deg_in
    int* mflag = (int*)w;               w += (size_t)N * 4;
    float* dinv_out = (float*)w;        w += (size_t)N * 4;
    float* dinv_in = (float*)w;         w += (size_t)N * 4;
    float* Wr1 = (float*)w;             w += (size_t)D * D * 4;
    float* Wr2 = (float*)w;             w += (size_t)D * D * 4;
    float* WrE = (float*)w;             w += (size_t)D * D * 4;
    float* WrD = (float*)w;             w += (size_t)D * D * 4;

    // zero cnt_src, cursor, mflag (contiguous 3*N ints) + output scalar
    hipMemsetAsync(cnt_src, 0, (size_t)3 * N * 4, stream);
    hipMemsetAsync(d_out, 0, sizeof(float), stream);

    k_build<<<(E + 255) / 256, 256, 0, stream>>>(src, dst, cnt_src, cursor, col);
    k_misc<<<358, 256, 0, stream>>>(
        (const float4*)W1, (const float4*)W2, (const float4*)We2d, (const float4*)Wd,
        (float4*)Wr1, (float4*)Wr2, (float4*)WrE, (float4*)WrD,
        cnt_src, cursor, dinv_out, dinv_in, mask_nodes, mflag);
    k_prep<<<(N * 32 + 255) / 256, 256, 0, stream>>>((const float4*)x, (const float4*)tok,
                                                     mflag, dinv_out, (half4*)Ah);
    int ndense = N / 8;     // 6250
    int nloss = MASKN / 8;  // 3125
    int nspmm = (N + 3) / 4;
    // conv1: agg (fp16 gather)
    k_spmm<<<nspmm, 256, 0, stream>>>((const half8*)Ah, (float4*)Bf, cursor, col, nullptr, N);
    // conv1 epilogue -> fp16, pre-scaled by deg_out^-0.5
    k_dense<true, true, false, true><<<ndense, 128, 0, stream>>>(
        Bf, nullptr, Ah, (const float4*)Wr1, b1, g1, be1, a1, dinv_in, dinv_out, nullptr);
    // conv2: agg
    k_spmm<<<nspmm, 256, 0, stream>>>((const half8*)Ah, (float4*)Bf, cursor, col, nullptr, N);
    // conv2 epilogue + encoder_to_decoder + re-mask + pre-scale -> fp16 (fused)
    k_dense23<<<ndense, 128, 0, stream>>>(
        Bf, Ah, (const float4*)Wr2, (const float4*)WrE, b2, g2, be2, a2,
        dinv_in, dinv_out, mflag);
    // conv3: agg, masked rows only
    k_spmm<<<(MASKN + 3) / 4, 256, 0, stream>>>((const half8*)Ah, (float4*)Bf, cursor, col,
                                                mask_nodes, MASKN);
    // decoder fc + SCE loss
    k_loss<<<nloss, 128, 0, stream>>>(Bf, x, (const float4*)WrD, bd,
                                      dinv_in, mask_nodes, (float*)d_out);
}

// Round 10
// 356.335 us; speedup vs baseline: 2.1706x; 1.2421x over previous
//
#include <hip/hip_runtime.h>

constexpr int N = 50000;
constexpr int E = 800000;
constexpr int D = 128;
constexpr int MASKN = 25000;
constexpr int CAP = 96; // bucket capacity; deg ~ Poisson(16), P(>96) ~ 0

typedef _Float16 half8 __attribute__((ext_vector_type(8)));
typedef _Float16 half4 __attribute__((ext_vector_type(4)));
typedef float f32x4 __attribute__((ext_vector_type(4)));

#define ROW8(X) X(0) X(1) X(2) X(3) X(4) X(5) X(6) X(7)

// ---------------- one-pass bucket build (device atomics — measured 77us,
// beats every atomic-free scheme tried; see R8 post-mortem) ----------------

__global__ void k_build(const int* __restrict__ src, const int* __restrict__ dst,
                        int* __restrict__ cnt_src, int* __restrict__ cursor,
                        unsigned short* __restrict__ col) {
    int e = blockIdx.x * blockDim.x + threadIdx.x;
    if (e < E) {
        int s = src[e], d = dst[e];
        atomicAdd(&cnt_src[s], 1);
        int p = atomicAdd(&cursor[d], 1);
        col[(size_t)d * CAP + p] = (unsigned short)s;
    }
}

// ---------------- fused setup: 4x W->fp16 cast + dinv + mflag ----------------
// MFMA B-operand wants W in ORIGINAL row-major [out][in] (lane reads 16B of
// contiguous k) — so this is a pure cast, no transpose.

__global__ void k_misc(const float* __restrict__ W1, const float* __restrict__ W2,
                       const float* __restrict__ WE, const float* __restrict__ WD,
                       _Float16* __restrict__ Wh1, _Float16* __restrict__ Wh2,
                       _Float16* __restrict__ WhE, _Float16* __restrict__ WhD,
                       const int* __restrict__ cs, const int* __restrict__ cd,
                       float* __restrict__ dinv_out, float* __restrict__ dinv_in,
                       const int* __restrict__ mask_nodes, int* __restrict__ mflag) {
    int b = blockIdx.x, t = threadIdx.x;
    if (b < 16) { // 4 matrices x 4 blocks, 4096 elems each
        int m = b >> 2;
        const float* W = m == 0 ? W1 : m == 1 ? W2 : m == 2 ? WE : WD;
        _Float16* Wh = m == 0 ? Wh1 : m == 1 ? Wh2 : m == 2 ? WhE : WhD;
        int base = (b & 3) * 4096 + t;
#pragma unroll
        for (int j = 0; j < 16; ++j) Wh[base + j * 256] = (_Float16)W[base + j * 256];
    } else if (b < 16 + 196) {
        int i = (b - 16) * 256 + t;
        if (i < N) {
            int a = cs[i] > 1 ? cs[i] : 1;
            int bb = cd[i] > 1 ? cd[i] : 1;
            dinv_out[i] = rsqrtf((float)a);
            dinv_in[i] = rsqrtf((float)bb);
        }
    } else {
        int i = (b - 212) * 256 + t;
        if (i < MASKN) mflag[mask_nodes[i]] = 1;
    }
}

// ---------------- feature prep: masked x scaled by deg_out^-0.5, fp16 out ----

__global__ void k_prep(const float4* __restrict__ x, const float4* __restrict__ tok,
                       const int* __restrict__ mflag, const float* __restrict__ dinv_out,
                       half4* __restrict__ Ah4) {
    int i = blockIdx.x * blockDim.x + threadIdx.x; // over N*32 float4s
    if (i < N * 32) {
        int row = i >> 5;
        int c = i & 31;
        float s = dinv_out[row];
        float4 v = mflag[row] ? tok[c] : x[i];
        half4 h;
        h[0] = (_Float16)(v.x * s);
        h[1] = (_Float16)(v.y * s);
        h[2] = (_Float16)(v.z * s);
        h[3] = (_Float16)(v.w * s);
        Ah4[i] = h;
    }
}

// ---------------- SpMM: B[row] = sum over bucket neighbors of Ah[col], fp16 out

__launch_bounds__(256)
__global__ void k_spmm(const half8* __restrict__ Ah8, half8* __restrict__ Bh8,
                       const int* __restrict__ deg, const unsigned short* __restrict__ col,
                       const int* __restrict__ rows, int nrows) {
    int wv = threadIdx.x >> 6, lane = threadIdx.x & 63;
    int q = lane >> 4, j = lane & 15;
    int rr = blockIdx.x * 4 + wv;
    if (rr >= nrows) return;
    int row = rows ? rows[rr] : rr;
    int dg = deg[row];
    const unsigned short* crow = col + (size_t)row * CAP;
    float a0 = 0.f, a1 = 0.f, a2 = 0.f, a3 = 0.f;
    float a4 = 0.f, a5 = 0.f, a6 = 0.f, a7 = 0.f;
    int e = q;
    for (; e + 4 < dg; e += 8) {
        int c0 = crow[e], c1 = crow[e + 4];
        half8 h0 = Ah8[(size_t)c0 * 16 + j];
        half8 h1 = Ah8[(size_t)c1 * 16 + j];
#define SP_ACC(i) a##i += (float)h0[i]; a##i += (float)h1[i];
        ROW8(SP_ACC)
#undef SP_ACC
    }
    if (e < dg) {
        int c0 = crow[e];
        half8 h0 = Ah8[(size_t)c0 * 16 + j];
#define SP_ACC1(i) a##i += (float)h0[i];
        ROW8(SP_ACC1)
#undef SP_ACC1
    }
#pragma unroll
    for (int o = 16; o <= 32; o <<= 1) {
#define SP_SHFL(i) a##i += __shfl_xor(a##i, o);
        ROW8(SP_SHFL)
#undef SP_SHFL
    }
    if (q == 0) {
        half8 ho;
#define SP_PACK(i) ho[i] = (_Float16)a##i;
        ROW8(SP_PACK)
#undef SP_PACK
        Bh8[(size_t)row * 16 + j] = ho;
    }
}

// ---------------- MFMA dense: 256 thr, 32 rows x 128 cols, K=128 -------------
// wave w -> cols [32w,32w+32); per wave 2x2 tiles of 16x16, 4 K-steps, 16 MFMA.
// A fp16 row-major (lane: row=lane&15, k=quad*8); B = W fp16 row-major.
// C (col=lane&15,row=quad*4+reg) -> LDS -> LN/epilogue.

template <bool LN, bool SCALE_OUT, bool MASK_ZERO>
__launch_bounds__(256)
__global__ void k_mf(const _Float16* __restrict__ Ain, _Float16* __restrict__ outh,
                     const _Float16* __restrict__ Wh,
                     const float* __restrict__ bias, const float* __restrict__ g,
                     const float* __restrict__ be, const float* __restrict__ aP,
                     const float* __restrict__ dinv_in, const float* __restrict__ dinv_out,
                     const int* __restrict__ mflag) {
    __shared__ float shc[32][132];
    __shared__ float smu[32], srs[32];
    int t = threadIdx.x;
    int w = t >> 6, lane = t & 63;
    int rl = lane & 15, quad = lane >> 4;
    int r0 = blockIdx.x * 32;
    int ra0 = r0 + rl;      if (ra0 > N - 1) ra0 = N - 1;
    int ra1 = r0 + 16 + rl; if (ra1 > N - 1) ra1 = N - 1;
    const half8* A0p = (const half8*)(Ain + (size_t)ra0 * 128 + quad * 8);
    const half8* A1p = (const half8*)(Ain + (size_t)ra1 * 128 + quad * 8);
    const half8* B0p = (const half8*)(Wh + (size_t)(w * 32 + rl) * 128 + quad * 8);
    const half8* B1p = (const half8*)(Wh + (size_t)(w * 32 + 16 + rl) * 128 + quad * 8);
    f32x4 c00 = {0.f, 0.f, 0.f, 0.f}, c01 = c00, c10 = c00, c11 = c00;
#pragma unroll
    for (int kk = 0; kk < 4; ++kk) {
        half8 a0 = A0p[kk * 4];
        half8 a1 = A1p[kk * 4];
        half8 b0 = B0p[kk * 4];
        half8 b1 = B1p[kk * 4];
        c00 = __builtin_amdgcn_mfma_f32_16x16x32_f16(a0, b0, c00, 0, 0, 0);
        c01 = __builtin_amdgcn_mfma_f32_16x16x32_f16(a0, b1, c01, 0, 0, 0);
        c10 = __builtin_amdgcn_mfma_f32_16x16x32_f16(a1, b0, c10, 0, 0, 0);
        c11 = __builtin_amdgcn_mfma_f32_16x16x32_f16(a1, b1, c11, 0, 0, 0);
    }
#pragma unroll
    for (int reg = 0; reg < 4; ++reg) {
        shc[quad * 4 + reg][w * 32 + rl] = c00[reg];
        shc[quad * 4 + reg][w * 32 + 16 + rl] = c01[reg];
        shc[16 + quad * 4 + reg][w * 32 + rl] = c10[reg];
        shc[16 + quad * 4 + reg][w * 32 + 16 + rl] = c11[reg];
    }
    __syncthreads();
    if constexpr (LN) {
        // per-row mu/rs: 8 threads per row, 16 cols each
        int row = t >> 3, seg = t & 7;
        int rr = r0 + row;
        float di = dinv_in[rr > N - 1 ? N - 1 : rr];
        float s = 0.f, q = 0.f;
#pragma unroll
        for (int c = 0; c < 16; ++c) {
            int cc = seg * 16 + c;
            float v = (shc[row][cc] + bias[cc]) * di;
            s += v;
            q += v * v;
        }
#pragma unroll
        for (int o = 1; o <= 4; o <<= 1) {
            s += __shfl_xor(s, o);
            q += __shfl_xor(q, o);
        }
        if (seg == 0) {
            float mu = s * (1.f / 128.f);
            float var = q * (1.f / 128.f) - mu * mu;
            smu[row] = mu;
            srs[row] = rsqrtf(var + 1e-5f);
        }
        __syncthreads();
    }
    // elementwise epilogue + store
    int tc = t & 127, rg = t >> 7;
    float gt = 0.f, bet = 0.f, bt = 0.f, alpha = 0.f;
    if constexpr (LN) {
        bt = bias[tc];
        gt = g[tc];
        bet = be[tc];
        alpha = aP[0];
    }
#pragma unroll
    for (int i = 0; i < 16; ++i) {
        int lr = rg * 16 + i;
        int r = r0 + lr;
        if (r < N) {
            float v = shc[lr][tc];
            if constexpr (LN) {
                v = (v + bt) * dinv_in[r];
                v = (v - smu[lr]) * srs[lr] * gt + bet;
                v = v >= 0.f ? v : alpha * v;
            }
            if (MASK_ZERO && mflag[r]) v = 0.f;
            if constexpr (SCALE_OUT) v *= dinv_out[r];
            outh[(size_t)r * 128 + tc] = (_Float16)v;
        }
    }
}

// ---------------- MFMA decoder fc + degnorm + SCE loss (gathered rows) -------

__launch_bounds__(256)
__global__ void k_mf_loss(const _Float16* __restrict__ Ain, const float* __restrict__ x,
                          const _Float16* __restrict__ Wh, const float* __restrict__ bd,
                          const float* __restrict__ dinv_in, const int* __restrict__ mask_nodes,
                          float* __restrict__ outp) {
    __shared__ float shc[32][132];
    __shared__ int shm[32];
    __shared__ float sterm[32];
    int t = threadIdx.x;
    int w = t >> 6, lane = t & 63;
    int rl = lane & 15, quad = lane >> 4;
    int i0 = blockIdx.x * 32;
    if (t < 32) {
        int idx = i0 + t;
        shm[t] = idx < MASKN ? mask_nodes[idx] : -1;
    }
    __syncthreads();
    int m0 = shm[rl], m1 = shm[16 + rl];
    int ga0 = m0 < 0 ? 0 : m0;
    int ga1 = m1 < 0 ? 0 : m1;
    const half8* A0p = (const half8*)(Ain + (size_t)ga0 * 128 + quad * 8);
    const half8* A1p = (const half8*)(Ain + (size_t)ga1 * 128 + quad * 8);
    const half8* B0p = (const half8*)(Wh + (size_t)(w * 32 + rl) * 128 + quad * 8);
    const half8* B1p = (const half8*)(Wh + (size_t)(w * 32 + 16 + rl) * 128 + quad * 8);
    f32x4 c00 = {0.f, 0.f, 0.f, 0.f}, c01 = c00, c10 = c00, c11 = c00;
#pragma unroll
    for (int kk = 0; kk < 4; ++kk) {
        half8 a0 = A0p[kk * 4];
        half8 a1 = A1p[kk * 4];
        half8 b0 = B0p[kk * 4];
        half8 b1 = B1p[kk * 4];
        c00 = __builtin_amdgcn_mfma_f32_16x16x32_f16(a0, b0, c00, 0, 0, 0);
        c01 = __builtin_amdgcn_mfma_f32_16x16x32_f16(a0, b1, c01, 0, 0, 0);
        c10 = __builtin_amdgcn_mfma_f32_16x16x32_f16(a1, b0, c10, 0, 0, 0);
        c11 = __builtin_amdgcn_mfma_f32_16x16x32_f16(a1, b1, c11, 0, 0, 0);
    }
#pragma unroll
    for (int reg = 0; reg < 4; ++reg) {
        shc[quad * 4 + reg][w * 32 + rl] = c00[reg];
        shc[quad * 4 + reg][w * 32 + 16 + rl] = c01[reg];
        shc[16 + quad * 4 + reg][w * 32 + rl] = c10[reg];
        shc[16 + quad * 4 + reg][w * 32 + 16 + rl] = c11[reg];
    }
    __syncthreads();
    // per-row loss: 8 threads/row
    int row = t >> 3, seg = t & 7;
    int m = shm[row];
    float a = 0.f, b = 0.f, c = 0.f;
    if (m >= 0) {
        float di = dinv_in[m];
#pragma unroll
        for (int cc0 = 0; cc0 < 16; ++cc0) {
            int cc = seg * 16 + cc0;
            float r = (shc[row][cc] + bd[cc]) * di;
            float xv = x[(size_t)m * 128 + cc];
            a += r * r;
            b += xv * xv;
            c += r * xv;
        }
    }
#pragma unroll
    for (int o = 1; o <= 4; o <<= 1) {
        a += __shfl_xor(a, o);
        b += __shfl_xor(b, o);
        c += __shfl_xor(c, o);
    }
    if (seg == 0) {
        float term = 0.f;
        if (m >= 0) {
            float nr = fmaxf(sqrtf(a), 1e-12f);
            float nx = fmaxf(sqrtf(b), 1e-12f);
            float d = 1.f - c / (nr * nx);
            term = d * d;
        }
        sterm[row] = term;
    }
    __syncthreads();
    if (t == 0) {
        float sum = 0.f;
#pragma unroll
        for (int i = 0; i < 32; ++i) sum += sterm[i];
        atomicAdd(outp, sum * (1.f / MASKN));
    }
}

// ---------------- launch ----------------

extern "C" void kernel_launch(void* const* d_in, const int* in_sizes, int n_in,
                              void* d_out, int out_size, void* d_ws, size_t ws_size,
                              hipStream_t stream) {
    const float* x = (const float*)d_in[0];
    const float* tok = (const float*)d_in[1];
    const float* W1 = (const float*)d_in[2];
    const float* b1 = (const float*)d_in[3];
    const float* g1 = (const float*)d_in[4];
    const float* be1 = (const float*)d_in[5];
    const float* a1 = (const float*)d_in[6];
    const float* W2 = (const float*)d_in[7];
    const float* b2 = (const float*)d_in[8];
    const float* g2 = (const float*)d_in[9];
    const float* be2 = (const float*)d_in[10];
    const float* a2 = (const float*)d_in[11];
    const float* We2d = (const float*)d_in[12];
    const float* Wd = (const float*)d_in[13];
    const float* bd = (const float*)d_in[14];
    const int* src = (const int*)d_in[15];
    const int* dst = (const int*)d_in[16];
    const int* mask_nodes = (const int*)d_in[17];

    char* w = (char*)d_ws;
    _Float16* Ah = (_Float16*)w;        w += (size_t)N * D * 2;
    _Float16* Bh = (_Float16*)w;        w += (size_t)N * D * 2;
    unsigned short* col = (unsigned short*)w; w += (size_t)N * CAP * 2;
    int* cnt_src = (int*)w;             w += (size_t)N * 4;
    int* cursor = (int*)w;              w += (size_t)N * 4; // becomes deg_in
    int* mflag = (int*)w;               w += (size_t)N * 4;
    float* dinv_out = (float*)w;        w += (size_t)N * 4;
    float* dinv_in = (float*)w;         w += (size_t)N * 4;
    _Float16* Wh1 = (_Float16*)w;       w += (size_t)D * D * 2;
    _Float16* Wh2 = (_Float16*)w;       w += (size_t)D * D * 2;
    _Float16* WhE = (_Float16*)w;       w += (size_t)D * D * 2;
    _Float16* WhD = (_Float16*)w;       w += (size_t)D * D * 2;

    // zero cnt_src, cursor, mflag (contiguous 3*N ints) + output scalar
    hipMemsetAsync(cnt_src, 0, (size_t)3 * N * 4, stream);
    hipMemsetAsync(d_out, 0, sizeof(float), stream);

    k_build<<<(E + 255) / 256, 256, 0, stream>>>(src, dst, cnt_src, cursor, col);
    k_misc<<<310, 256, 0, stream>>>(W1, W2, We2d, Wd, Wh1, Wh2, WhE, WhD,
                                    cnt_src, cursor, dinv_out, dinv_in, mask_nodes, mflag);
    k_prep<<<(N * 32 + 255) / 256, 256, 0, stream>>>((const float4*)x, (const float4*)tok,
                                                     mflag, dinv_out, (half4*)Ah);
    int nmf = (N + 31) / 32;        // 1563
    int nmfl = (MASKN + 31) / 32;   // 782
    int nspmm = (N + 3) / 4;
    // conv1: agg (fp16 gather, fp16 out)
    k_spmm<<<nspmm, 256, 0, stream>>>((const half8*)Ah, (half8*)Bh, cursor, col, nullptr, N);
    // conv1 epilogue (MFMA): fc + in-deg norm + LN + PReLU, pre-scale deg_out^-0.5
    k_mf<true, true, false><<<nmf, 256, 0, stream>>>(
        Bh, Ah, Wh1, b1, g1, be1, a1, dinv_in, dinv_out, nullptr);
    // conv2: agg
    k_spmm<<<nspmm, 256, 0, stream>>>((const half8*)Ah, (half8*)Bh, cursor, col, nullptr, N);
    // conv2 epilogue (MFMA): h2
    k_mf<true, false, false><<<nmf, 256, 0, stream>>>(
        Bh, Ah, Wh2, b2, g2, be2, a2, dinv_in, dinv_out, nullptr);
    // encoder_to_decoder (MFMA) + re-mask + pre-scale
    k_mf<false, true, true><<<nmf, 256, 0, stream>>>(
        Ah, Bh, WhE, nullptr, nullptr, nullptr, nullptr, dinv_in, dinv_out, mflag);
    // conv3: agg, masked rows only
    k_spmm<<<(MASKN + 3) / 4, 256, 0, stream>>>((const half8*)Bh, (half8*)Ah, cursor, col,
                                                mask_nodes, MASKN);
    // decoder fc + SCE loss (MFMA)
    k_mf_loss<<<nmfl, 256, 0, stream>>>(Ah, x, WhD, bd, dinv_in, mask_nodes, (float*)d_out);
}

// Round 11
// 337.854 us; speedup vs baseline: 2.2893x; 1.0547x over previous
//
#include <hip/hip_runtime.h>

constexpr int N = 50000;
constexpr int E = 800000;
constexpr int D = 128;
constexpr int MASKN = 25000;
constexpr int CAP = 96; // bucket capacity; deg ~ Poisson(16), P(>96) ~ 0

typedef _Float16 half8 __attribute__((ext_vector_type(8)));
typedef _Float16 half4 __attribute__((ext_vector_type(4)));
typedef _Float16 half2v __attribute__((ext_vector_type(2)));
typedef float f32x4 __attribute__((ext_vector_type(4)));

#define ROW8(X) X(0) X(1) X(2) X(3) X(4) X(5) X(6) X(7)

// ---------------- one-pass bucket build (device atomics — measured ~80us,
// ~19G atomics/s ≈ device-atomic floor; atomic-free variants all lost) -------

__global__ void k_build(const int* __restrict__ src, const int* __restrict__ dst,
                        int* __restrict__ cnt_src, int* __restrict__ cursor,
                        unsigned short* __restrict__ col) {
    int e = blockIdx.x * blockDim.x + threadIdx.x;
    if (e < E) {
        int s = src[e], d = dst[e];
        atomicAdd(&cnt_src[s], 1);
        int p = atomicAdd(&cursor[d], 1);
        col[(size_t)d * CAP + p] = (unsigned short)s;
    }
}

// ---------------- fused setup: 4x W->fp16 cast + dinv + mflag ----------------

__global__ void k_misc(const float* __restrict__ W1, const float* __restrict__ W2,
                       const float* __restrict__ WE, const float* __restrict__ WD,
                       _Float16* __restrict__ Wh1, _Float16* __restrict__ Wh2,
                       _Float16* __restrict__ WhE, _Float16* __restrict__ WhD,
                       const int* __restrict__ cs, const int* __restrict__ cd,
                       float* __restrict__ dinv_out, float* __restrict__ dinv_in,
                       const int* __restrict__ mask_nodes, int* __restrict__ mflag) {
    int b = blockIdx.x, t = threadIdx.x;
    if (b < 16) { // 4 matrices x 4 blocks, 4096 elems each
        int m = b >> 2;
        const float* W = m == 0 ? W1 : m == 1 ? W2 : m == 2 ? WE : WD;
        _Float16* Wh = m == 0 ? Wh1 : m == 1 ? Wh2 : m == 2 ? WhE : WhD;
        int base = (b & 3) * 4096 + t;
#pragma unroll
        for (int j = 0; j < 16; ++j) Wh[base + j * 256] = (_Float16)W[base + j * 256];
    } else if (b < 16 + 196) {
        int i = (b - 16) * 256 + t;
        if (i < N) {
            int a = cs[i] > 1 ? cs[i] : 1;
            int bb = cd[i] > 1 ? cd[i] : 1;
            dinv_out[i] = rsqrtf((float)a);
            dinv_in[i] = rsqrtf((float)bb);
        }
    } else {
        int i = (b - 212) * 256 + t;
        if (i < MASKN) mflag[mask_nodes[i]] = 1;
    }
}

// ---------------- feature prep: masked x scaled by deg_out^-0.5, fp16 out ----

__global__ void k_prep(const float4* __restrict__ x, const float4* __restrict__ tok,
                       const int* __restrict__ mflag, const float* __restrict__ dinv_out,
                       half4* __restrict__ Ah4) {
    int i = blockIdx.x * blockDim.x + threadIdx.x; // over N*32 float4s
    if (i < N * 32) {
        int row = i >> 5;
        int c = i & 31;
        float s = dinv_out[row];
        float4 v = mflag[row] ? tok[c] : x[i];
        half4 h;
        h[0] = (_Float16)(v.x * s);
        h[1] = (_Float16)(v.y * s);
        h[2] = (_Float16)(v.z * s);
        h[3] = (_Float16)(v.w * s);
        Ah4[i] = h;
    }
}

// ---------------- SpMM: B[row] = sum over bucket neighbors of Ah[col], fp16 out
// quarter-wave per edge; 16-edge unroll keeps 4 gathers in flight (deg~16 rows
// finish in one iteration).

__launch_bounds__(256)
__global__ void k_spmm(const half8* __restrict__ Ah8, half8* __restrict__ Bh8,
                       const int* __restrict__ deg, const unsigned short* __restrict__ col,
                       const int* __restrict__ rows, int nrows) {
    int wv = threadIdx.x >> 6, lane = threadIdx.x & 63;
    int q = lane >> 4, j = lane & 15;
    int rr = blockIdx.x * 4 + wv;
    if (rr >= nrows) return;
    int row = rows ? rows[rr] : rr;
    int dg = deg[row];
    const unsigned short* crow = col + (size_t)row * CAP;
    float a0 = 0.f, a1 = 0.f, a2 = 0.f, a3 = 0.f;
    float a4 = 0.f, a5 = 0.f, a6 = 0.f, a7 = 0.f;
    int e = q;
    for (; e + 12 < dg; e += 16) {
        int c0 = crow[e], c1 = crow[e + 4], c2 = crow[e + 8], c3 = crow[e + 12];
        half8 h0 = Ah8[(size_t)c0 * 16 + j];
        half8 h1 = Ah8[(size_t)c1 * 16 + j];
        half8 h2 = Ah8[(size_t)c2 * 16 + j];
        half8 h3 = Ah8[(size_t)c3 * 16 + j];
#define SP_ACC4(i) a##i += (float)h0[i]; a##i += (float)h1[i];                 \
                   a##i += (float)h2[i]; a##i += (float)h3[i];
        ROW8(SP_ACC4)
#undef SP_ACC4
    }
    for (; e + 4 < dg; e += 8) {
        int c0 = crow[e], c1 = crow[e + 4];
        half8 h0 = Ah8[(size_t)c0 * 16 + j];
        half8 h1 = Ah8[(size_t)c1 * 16 + j];
#define SP_ACC(i) a##i += (float)h0[i]; a##i += (float)h1[i];
        ROW8(SP_ACC)
#undef SP_ACC
    }
    if (e < dg) {
        int c0 = crow[e];
        half8 h0 = Ah8[(size_t)c0 * 16 + j];
#define SP_ACC1(i) a##i += (float)h0[i];
        ROW8(SP_ACC1)
#undef SP_ACC1
    }
#pragma unroll
    for (int o = 16; o <= 32; o <<= 1) {
#define SP_SHFL(i) a##i += __shfl_xor(a##i, o);
        ROW8(SP_SHFL)
#undef SP_SHFL
    }
    if (q == 0) {
        half8 ho;
#define SP_PACK(i) ho[i] = (_Float16)a##i;
        ROW8(SP_PACK)
#undef SP_PACK
        Bh8[(size_t)row * 16 + j] = ho;
    }
}

// ---------------- MFMA dense: 256 thr, 32 rows x 128 cols, K=128 -------------
// verified layout (R10, absmax 0): A lane row=lane&15 k=quad*8; B = W row-major;
// C col=lane&15, row=quad*4+reg.

template <bool LN, bool SCALE_OUT, bool MASK_ZERO>
__launch_bounds__(256)
__global__ void k_mf(const _Float16* __restrict__ Ain, _Float16* __restrict__ outh,
                     const _Float16* __restrict__ Wh,
                     const float* __restrict__ bias, const float* __restrict__ g,
                     const float* __restrict__ be, const float* __restrict__ aP,
                     const float* __restrict__ dinv_in, const float* __restrict__ dinv_out,
                     const int* __restrict__ mflag) {
    __shared__ float shc[32][132];
    __shared__ float smu[32], srs[32];
    int t = threadIdx.x;
    int w = t >> 6, lane = t & 63;
    int rl = lane & 15, quad = lane >> 4;
    int r0 = blockIdx.x * 32;
    int ra0 = r0 + rl;      if (ra0 > N - 1) ra0 = N - 1;
    int ra1 = r0 + 16 + rl; if (ra1 > N - 1) ra1 = N - 1;
    const half8* A0p = (const half8*)(Ain + (size_t)ra0 * 128 + quad * 8);
    const half8* A1p = (const half8*)(Ain + (size_t)ra1 * 128 + quad * 8);
    const half8* B0p = (const half8*)(Wh + (size_t)(w * 32 + rl) * 128 + quad * 8);
    const half8* B1p = (const half8*)(Wh + (size_t)(w * 32 + 16 + rl) * 128 + quad * 8);
    f32x4 c00 = {0.f, 0.f, 0.f, 0.f}, c01 = c00, c10 = c00, c11 = c00;
#pragma unroll
    for (int kk = 0; kk < 4; ++kk) {
        half8 a0 = A0p[kk * 4];
        half8 a1 = A1p[kk * 4];
        half8 b0 = B0p[kk * 4];
        half8 b1 = B1p[kk * 4];
        c00 = __builtin_amdgcn_mfma_f32_16x16x32_f16(a0, b0, c00, 0, 0, 0);
        c01 = __builtin_amdgcn_mfma_f32_16x16x32_f16(a0, b1, c01, 0, 0, 0);
        c10 = __builtin_amdgcn_mfma_f32_16x16x32_f16(a1, b0, c10, 0, 0, 0);
        c11 = __builtin_amdgcn_mfma_f32_16x16x32_f16(a1, b1, c11, 0, 0, 0);
    }
#pragma unroll
    for (int reg = 0; reg < 4; ++reg) {
        shc[quad * 4 + reg][w * 32 + rl] = c00[reg];
        shc[quad * 4 + reg][w * 32 + 16 + rl] = c01[reg];
        shc[16 + quad * 4 + reg][w * 32 + rl] = c10[reg];
        shc[16 + quad * 4 + reg][w * 32 + 16 + rl] = c11[reg];
    }
    __syncthreads();
    if constexpr (LN) {
        int row = t >> 3, seg = t & 7;
        int rr = r0 + row;
        float di = dinv_in[rr > N - 1 ? N - 1 : rr];
        float s = 0.f, q = 0.f;
#pragma unroll
        for (int c = 0; c < 16; ++c) {
            int cc = seg * 16 + c;
            float v = (shc[row][cc] + bias[cc]) * di;
            s += v;
            q += v * v;
        }
#pragma unroll
        for (int o = 1; o <= 4; o <<= 1) {
            s += __shfl_xor(s, o);
            q += __shfl_xor(q, o);
        }
        if (seg == 0) {
            float mu = s * (1.f / 128.f);
            float var = q * (1.f / 128.f) - mu * mu;
            smu[row] = mu;
            srs[row] = rsqrtf(var + 1e-5f);
        }
        __syncthreads();
    }
    // epilogue: 4 groups of 8 rows, 2 cols/thread, half2 stores
    int lane64 = t & 63, grp = t >> 6;
    int cc0 = lane64 * 2, cc1 = cc0 + 1;
    float bt0 = 0.f, bt1 = 0.f, gt0 = 0.f, gt1 = 0.f, be0 = 0.f, be1 = 0.f, alpha = 0.f;
    if constexpr (LN) {
        bt0 = bias[cc0]; bt1 = bias[cc1];
        gt0 = g[cc0]; gt1 = g[cc1];
        be0 = be[cc0]; be1 = be[cc1];
        alpha = aP[0];
    }
#pragma unroll
    for (int i = 0; i < 8; ++i) {
        int lr = grp * 8 + i, r = r0 + lr;
        if (r < N) {
            float v0 = shc[lr][cc0], v1 = shc[lr][cc1];
            if constexpr (LN) {
                float di = dinv_in[r];
                v0 = (v0 + bt0) * di;
                v1 = (v1 + bt1) * di;
                float mu = smu[lr], rs = srs[lr];
                v0 = (v0 - mu) * rs * gt0 + be0;
                v1 = (v1 - mu) * rs * gt1 + be1;
                v0 = v0 >= 0.f ? v0 : alpha * v0;
                v1 = v1 >= 0.f ? v1 : alpha * v1;
            }
            if (MASK_ZERO && mflag[r]) { v0 = 0.f; v1 = 0.f; }
            if constexpr (SCALE_OUT) {
                float so = dinv_out[r];
                v0 *= so; v1 *= so;
            }
            half2v hv;
            hv[0] = (_Float16)v0;
            hv[1] = (_Float16)v1;
            *(half2v*)(outh + (size_t)r * 128 + cc0) = hv;
        }
    }
}

// ---------------- fused conv2-epilogue + encoder_to_decoder (MFMA x2) --------
// phase A: agg2 @ W2 + LN + PReLU -> h2 fp16 in LDS (stride 136 halfs: 16B-
// aligned, 2-way bank conflict only). phase B: h2 @ We2d, re-mask, *dinv_out,
// register-direct epilogue -> rep fp16.

__launch_bounds__(256)
__global__ void k_mf2(const _Float16* __restrict__ Ain, _Float16* __restrict__ outh,
                      const _Float16* __restrict__ Wh2, const _Float16* __restrict__ WhE,
                      const float* __restrict__ bias, const float* __restrict__ g,
                      const float* __restrict__ be, const float* __restrict__ aP,
                      const float* __restrict__ dinv_in, const float* __restrict__ dinv_out,
                      const int* __restrict__ mflag) {
    __shared__ float shc[32][132];
    __shared__ _Float16 shh[32][136];
    __shared__ float smu[32], srs[32], sdo[32];
    __shared__ int smf[32];
    int t = threadIdx.x;
    int w = t >> 6, lane = t & 63;
    int rl = lane & 15, quad = lane >> 4;
    int r0 = blockIdx.x * 32;
    if (t < 32) {
        int r = r0 + t;
        int rc = r > N - 1 ? N - 1 : r;
        sdo[t] = dinv_out[rc];
        smf[t] = mflag[rc];
    }
    int ra0 = r0 + rl;      if (ra0 > N - 1) ra0 = N - 1;
    int ra1 = r0 + 16 + rl; if (ra1 > N - 1) ra1 = N - 1;
    const half8* A0p = (const half8*)(Ain + (size_t)ra0 * 128 + quad * 8);
    const half8* A1p = (const half8*)(Ain + (size_t)ra1 * 128 + quad * 8);
    const half8* B0p = (const half8*)(Wh2 + (size_t)(w * 32 + rl) * 128 + quad * 8);
    const half8* B1p = (const half8*)(Wh2 + (size_t)(w * 32 + 16 + rl) * 128 + quad * 8);
    f32x4 c00 = {0.f, 0.f, 0.f, 0.f}, c01 = c00, c10 = c00, c11 = c00;
#pragma unroll
    for (int kk = 0; kk < 4; ++kk) {
        half8 a0 = A0p[kk * 4];
        half8 a1 = A1p[kk * 4];
        half8 b0 = B0p[kk * 4];
        half8 b1 = B1p[kk * 4];
        c00 = __builtin_amdgcn_mfma_f32_16x16x32_f16(a0, b0, c00, 0, 0, 0);
        c01 = __builtin_amdgcn_mfma_f32_16x16x32_f16(a0, b1, c01, 0, 0, 0);
        c10 = __builtin_amdgcn_mfma_f32_16x16x32_f16(a1, b0, c10, 0, 0, 0);
        c11 = __builtin_amdgcn_mfma_f32_16x16x32_f16(a1, b1, c11, 0, 0, 0);
    }
#pragma unroll
    for (int reg = 0; reg < 4; ++reg) {
        shc[quad * 4 + reg][w * 32 + rl] = c00[reg];
        shc[quad * 4 + reg][w * 32 + 16 + rl] = c01[reg];
        shc[16 + quad * 4 + reg][w * 32 + rl] = c10[reg];
        shc[16 + quad * 4 + reg][w * 32 + 16 + rl] = c11[reg];
    }
    __syncthreads();
    { // LN stats
        int row = t >> 3, seg = t & 7;
        int rr = r0 + row;
        float di = dinv_in[rr > N - 1 ? N - 1 : rr];
        float s = 0.f, q = 0.f;
#pragma unroll
        for (int c = 0; c < 16; ++c) {
            int cc = seg * 16 + c;
            float v = (shc[row][cc] + bias[cc]) * di;
            s += v;
            q += v * v;
        }
#pragma unroll
        for (int o = 1; o <= 4; o <<= 1) {
            s += __shfl_xor(s, o);
            q += __shfl_xor(q, o);
        }
        if (seg == 0) {
            float mu = s * (1.f / 128.f);
            float var = q * (1.f / 128.f) - mu * mu;
            smu[row] = mu;
            srs[row] = rsqrtf(var + 1e-5f);
        }
        __syncthreads();
    }
    { // h2 -> shh (fp16)
        int lane64 = t & 63, grp = t >> 6;
        int cc0 = lane64 * 2, cc1 = cc0 + 1;
        float bt0 = bias[cc0], bt1 = bias[cc1];
        float gt0 = g[cc0], gt1 = g[cc1];
        float be0 = be[cc0], be1 = be[cc1];
        float alpha = aP[0];
#pragma unroll
        for (int i = 0; i < 8; ++i) {
            int lr = grp * 8 + i, r = r0 + lr;
            float v0 = 0.f, v1 = 0.f;
            if (r < N) {
                float di = dinv_in[r];
                v0 = (shc[lr][cc0] + bt0) * di;
                v1 = (shc[lr][cc1] + bt1) * di;
                float mu = smu[lr], rs = srs[lr];
                v0 = (v0 - mu) * rs * gt0 + be0;
                v1 = (v1 - mu) * rs * gt1 + be1;
                v0 = v0 >= 0.f ? v0 : alpha * v0;
                v1 = v1 >= 0.f ? v1 : alpha * v1;
            }
            shh[lr][cc0] = (_Float16)v0;
            shh[lr][cc1] = (_Float16)v1;
        }
    }
    __syncthreads();
    // phase B: rep = h2 @ We2d
    const half8* E0p = (const half8*)(WhE + (size_t)(w * 32 + rl) * 128 + quad * 8);
    const half8* E1p = (const half8*)(WhE + (size_t)(w * 32 + 16 + rl) * 128 + quad * 8);
    f32x4 d00 = {0.f, 0.f, 0.f, 0.f}, d01 = d00, d10 = d00, d11 = d00;
#pragma unroll
    for (int kk = 0; kk < 4; ++kk) {
        half8 a0 = *(const half8*)&shh[rl][kk * 32 + quad * 8];
        half8 a1 = *(const half8*)&shh[16 + rl][kk * 32 + quad * 8];
        half8 b0 = E0p[kk * 4];
        half8 b1 = E1p[kk * 4];
        d00 = __builtin_amdgcn_mfma_f32_16x16x32_f16(a0, b0, d00, 0, 0, 0);
        d01 = __builtin_amdgcn_mfma_f32_16x16x32_f16(a0, b1, d01, 0, 0, 0);
        d10 = __builtin_amdgcn_mfma_f32_16x16x32_f16(a1, b0, d10, 0, 0, 0);
        d11 = __builtin_amdgcn_mfma_f32_16x16x32_f16(a1, b1, d11, 0, 0, 0);
    }
    // register-direct epilogue: re-mask + dinv_out scale
#pragma unroll
    for (int reg = 0; reg < 4; ++reg) {
        int lr = quad * 4 + reg, r = r0 + lr;
        if (r < N) {
            float s = smf[lr] ? 0.f : sdo[lr];
            outh[(size_t)r * 128 + w * 32 + rl] = (_Float16)(d00[reg] * s);
            outh[(size_t)r * 128 + w * 32 + 16 + rl] = (_Float16)(d01[reg] * s);
        }
        int lr2 = 16 + lr, r2 = r0 + lr2;
        if (r2 < N) {
            float s = smf[lr2] ? 0.f : sdo[lr2];
            outh[(size_t)r2 * 128 + w * 32 + rl] = (_Float16)(d10[reg] * s);
            outh[(size_t)r2 * 128 + w * 32 + 16 + rl] = (_Float16)(d11[reg] * s);
        }
    }
}

// ---------------- MFMA decoder fc + degnorm + SCE loss (gathered rows) -------

__launch_bounds__(256)
__global__ void k_mf_loss(const _Float16* __restrict__ Ain, const float* __restrict__ x,
                          const _Float16* __restrict__ Wh, const float* __restrict__ bd,
                          const float* __restrict__ dinv_in, const int* __restrict__ mask_nodes,
                          float* __restrict__ outp) {
    __shared__ float shc[32][132];
    __shared__ int shm[32];
    __shared__ float sterm[32];
    int t = threadIdx.x;
    int w = t >> 6, lane = t & 63;
    int rl = lane & 15, quad = lane >> 4;
    int i0 = blockIdx.x * 32;
    if (t < 32) {
        int idx = i0 + t;
        shm[t] = idx < MASKN ? mask_nodes[idx] : -1;
    }
    __syncthreads();
    int m0 = shm[rl], m1 = shm[16 + rl];
    int ga0 = m0 < 0 ? 0 : m0;
    int ga1 = m1 < 0 ? 0 : m1;
    const half8* A0p = (const half8*)(Ain + (size_t)ga0 * 128 + quad * 8);
    const half8* A1p = (const half8*)(Ain + (size_t)ga1 * 128 + quad * 8);
    const half8* B0p = (const half8*)(Wh + (size_t)(w * 32 + rl) * 128 + quad * 8);
    const half8* B1p = (const half8*)(Wh + (size_t)(w * 32 + 16 + rl) * 128 + quad * 8);
    f32x4 c00 = {0.f, 0.f, 0.f, 0.f}, c01 = c00, c10 = c00, c11 = c00;
#pragma unroll
    for (int kk = 0; kk < 4; ++kk) {
        half8 a0 = A0p[kk * 4];
        half8 a1 = A1p[kk * 4];
        half8 b0 = B0p[kk * 4];
        half8 b1 = B1p[kk * 4];
        c00 = __builtin_amdgcn_mfma_f32_16x16x32_f16(a0, b0, c00, 0, 0, 0);
        c01 = __builtin_amdgcn_mfma_f32_16x16x32_f16(a0, b1, c01, 0, 0, 0);
        c10 = __builtin_amdgcn_mfma_f32_16x16x32_f16(a1, b0, c10, 0, 0, 0);
        c11 = __builtin_amdgcn_mfma_f32_16x16x32_f16(a1, b1, c11, 0, 0, 0);
    }
#pragma unroll
    for (int reg = 0; reg < 4; ++reg) {
        shc[quad * 4 + reg][w * 32 + rl] = c00[reg];
        shc[quad * 4 + reg][w * 32 + 16 + rl] = c01[reg];
        shc[16 + quad * 4 + reg][w * 32 + rl] = c10[reg];
        shc[16 + quad * 4 + reg][w * 32 + 16 + rl] = c11[reg];
    }
    __syncthreads();
    int row = t >> 3, seg = t & 7;
    int m = shm[row];
    float a = 0.f, b = 0.f, c = 0.f;
    if (m >= 0) {
        float di = dinv_in[m];
#pragma unroll
        for (int cc0 = 0; cc0 < 16; ++cc0) {
            int cc = seg * 16 + cc0;
            float r = (shc[row][cc] + bd[cc]) * di;
            float xv = x[(size_t)m * 128 + cc];
            a += r * r;
            b += xv * xv;
            c += r * xv;
        }
    }
#pragma unroll
    for (int o = 1; o <= 4; o <<= 1) {
        a += __shfl_xor(a, o);
        b += __shfl_xor(b, o);
        c += __shfl_xor(c, o);
    }
    if (seg == 0) {
        float term = 0.f;
        if (m >= 0) {
            float nr = fmaxf(sqrtf(a), 1e-12f);
            float nx = fmaxf(sqrtf(b), 1e-12f);
            float d = 1.f - c / (nr * nx);
            term = d * d;
        }
        sterm[row] = term;
    }
    __syncthreads();
    if (t == 0) {
        float sum = 0.f;
#pragma unroll
        for (int i = 0; i < 32; ++i) sum += sterm[i];
        atomicAdd(outp, sum * (1.f / MASKN));
    }
}

// ---------------- launch ----------------

extern "C" void kernel_launch(void* const* d_in, const int* in_sizes, int n_in,
                              void* d_out, int out_size, void* d_ws, size_t ws_size,
                              hipStream_t stream) {
    const float* x = (const float*)d_in[0];
    const float* tok = (const float*)d_in[1];
    const float* W1 = (const float*)d_in[2];
    const float* b1 = (const float*)d_in[3];
    const float* g1 = (const float*)d_in[4];
    const float* be1 = (const float*)d_in[5];
    const float* a1 = (const float*)d_in[6];
    const float* W2 = (const float*)d_in[7];
    const float* b2 = (const float*)d_in[8];
    const float* g2 = (const float*)d_in[9];
    const float* be2 = (const float*)d_in[10];
    const float* a2 = (const float*)d_in[11];
    const float* We2d = (const float*)d_in[12];
    const float* Wd = (const float*)d_in[13];
    const float* bd = (const float*)d_in[14];
    const int* src = (const int*)d_in[15];
    const int* dst = (const int*)d_in[16];
    const int* mask_nodes = (const int*)d_in[17];

    char* w = (char*)d_ws;
    _Float16* Ah = (_Float16*)w;        w += (size_t)N * D * 2;
    _Float16* Bh = (_Float16*)w;        w += (size_t)N * D * 2;
    unsigned short* col = (unsigned short*)w; w += (size_t)N * CAP * 2;
    int* cnt_src = (int*)w;             w += (size_t)N * 4;
    int* cursor = (int*)w;              w += (size_t)N * 4; // becomes deg_in
    int* mflag = (int*)w;               w += (size_t)N * 4;
    float* dinv_out = (float*)w;        w += (size_t)N * 4;
    float* dinv_in = (float*)w;         w += (size_t)N * 4;
    _Float16* Wh1 = (_Float16*)w;       w += (size_t)D * D * 2;
    _Float16* Wh2 = (_Float16*)w;       w += (size_t)D * D * 2;
    _Float16* WhE = (_Float16*)w;       w += (size_t)D * D * 2;
    _Float16* WhD = (_Float16*)w;       w += (size_t)D * D * 2;

    // zero cnt_src, cursor, mflag (contiguous 3*N ints) + output scalar
    hipMemsetAsync(cnt_src, 0, (size_t)3 * N * 4, stream);
    hipMemsetAsync(d_out, 0, sizeof(float), stream);

    k_build<<<(E + 255) / 256, 256, 0, stream>>>(src, dst, cnt_src, cursor, col);
    k_misc<<<310, 256, 0, stream>>>(W1, W2, We2d, Wd, Wh1, Wh2, WhE, WhD,
                                    cnt_src, cursor, dinv_out, dinv_in, mask_nodes, mflag);
    k_prep<<<(N * 32 + 255) / 256, 256, 0, stream>>>((const float4*)x, (const float4*)tok,
                                                     mflag, dinv_out, (half4*)Ah);
    int nmf = (N + 31) / 32;        // 1563
    int nmfl = (MASKN + 31) / 32;   // 782
    int nspmm = (N + 3) / 4;
    // conv1: agg (fp16 gather, fp16 out)
    k_spmm<<<nspmm, 256, 0, stream>>>((const half8*)Ah, (half8*)Bh, cursor, col, nullptr, N);
    // conv1 epilogue (MFMA): fc + in-deg norm + LN + PReLU, pre-scale deg_out^-0.5
    k_mf<true, true, false><<<nmf, 256, 0, stream>>>(
        Bh, Ah, Wh1, b1, g1, be1, a1, dinv_in, dinv_out, nullptr);
    // conv2: agg
    k_spmm<<<nspmm, 256, 0, stream>>>((const half8*)Ah, (half8*)Bh, cursor, col, nullptr, N);
    // conv2 epilogue + encoder_to_decoder + re-mask + pre-scale (fused, MFMA x2)
    k_mf2<<<nmf, 256, 0, stream>>>(
        Bh, Ah, Wh2, WhE, b2, g2, be2, a2, dinv_in, dinv_out, mflag);
    // conv3: agg, masked rows only
    k_spmm<<<(MASKN + 3) / 4, 256, 0, stream>>>((const half8*)Ah, (half8*)Bh, cursor, col,
                                                mask_nodes, MASKN);
    // decoder fc + SCE loss (MFMA)
    k_mf_loss<<<nmfl, 256, 0, stream>>>(Bh, x, WhD, bd, dinv_in, mask_nodes, (float*)d_out);
}

// Round 12
// 321.019 us; speedup vs baseline: 2.4094x; 1.0524x over previous
//
#include <hip/hip_runtime.h>

constexpr int N = 50000;
constexpr int E = 800000;
constexpr int D = 128;
constexpr int MASKN = 25000;
constexpr int CAP = 96; // bucket capacity; deg ~ Poisson(16), P(>96) ~ 0
constexpr int HB = 128;           // histogram blocks
constexpr int HW = (N + 1) / 2;   // packed 2x16-bit words

typedef _Float16 half8 __attribute__((ext_vector_type(8)));
typedef _Float16 half4 __attribute__((ext_vector_type(4)));
typedef _Float16 half2v __attribute__((ext_vector_type(2)));
typedef float f32x4 __attribute__((ext_vector_type(4)));

#define ROW8(X) X(0) X(1) X(2) X(3) X(4) X(5) X(6) X(7)

// ---------------- bucket build: cursor atomic + scatter only ----------------
// (cnt_src histogram moved to k_hist; this halves the device-atomic load)

__global__ void k_build(const int* __restrict__ src, const int* __restrict__ dst,
                        int* __restrict__ cursor, unsigned short* __restrict__ col) {
    int e = blockIdx.x * blockDim.x + threadIdx.x;
    if (e < E) {
        int s = src[e], d = dst[e];
        int p = atomicAdd(&cursor[d], 1);
        col[(size_t)d * CAP + p] = (unsigned short)s;
    }
}

// ---------------- out-degree histogram: LDS-privatized, packed 2x16-bit ------
// each block scans its OWN 6250-edge slice (no rescans); per-block count
// <= 6250 < 65536 so the packed halves never carry.

__launch_bounds__(256)
__global__ void k_hist(const int* __restrict__ src, unsigned int* __restrict__ partial) {
    __shared__ unsigned int hcnt[HW];
    int b = blockIdx.x, t = threadIdx.x;
    for (int i = t; i < HW; i += 256) hcnt[i] = 0u;
    __syncthreads();
    constexpr int PER = E / HB; // 6250
    int base = b * PER;
    for (int i = t; i < PER; i += 256) {
        int s = src[base + i];
        atomicAdd(&hcnt[s >> 1], 1u << ((s & 1) * 16));
    }
    __syncthreads();
    unsigned int* outp = partial + (size_t)b * HW;
    for (int i = t; i < HW; i += 256) outp[i] = hcnt[i];
}

// ---------------- fused setup: 4x W->fp16 cast + dinv (partial-sum) + mflag --

__global__ void k_misc(const float* __restrict__ W1, const float* __restrict__ W2,
                       const float* __restrict__ WE, const float* __restrict__ WD,
                       _Float16* __restrict__ Wh1, _Float16* __restrict__ Wh2,
                       _Float16* __restrict__ WhE, _Float16* __restrict__ WhD,
                       const unsigned int* __restrict__ partial,
                       const int* __restrict__ cd,
                       float* __restrict__ dinv_out, float* __restrict__ dinv_in,
                       const int* __restrict__ mask_nodes, int* __restrict__ mflag) {
    int b = blockIdx.x, t = threadIdx.x;
    if (b < 16) { // 4 matrices x 4 blocks, 4096 elems each
        int m = b >> 2;
        const float* W = m == 0 ? W1 : m == 1 ? W2 : m == 2 ? WE : WD;
        _Float16* Wh = m == 0 ? Wh1 : m == 1 ? Wh2 : m == 2 ? WhE : WhD;
        int base = (b & 3) * 4096 + t;
#pragma unroll
        for (int j = 0; j < 16; ++j) Wh[base + j * 256] = (_Float16)W[base + j * 256];
    } else if (b < 16 + 196) {
        int i = (b - 16) * 256 + t;
        if (i < N) {
            int word = i >> 1, sh = (i & 1) * 16;
            unsigned int sum = 0;
#pragma unroll 8
            for (int bb = 0; bb < HB; ++bb)
                sum += (partial[(size_t)bb * HW + word] >> sh) & 0xffffu;
            int a = sum > 1u ? (int)sum : 1;
            int bb2 = cd[i] > 1 ? cd[i] : 1;
            dinv_out[i] = rsqrtf((float)a);
            dinv_in[i] = rsqrtf((float)bb2);
        }
    } else {
        int i = (b - 212) * 256 + t;
        if (i < MASKN) mflag[mask_nodes[i]] = 1;
    }
}

// ---------------- feature prep: masked x scaled by deg_out^-0.5, fp16 out ----

__global__ void k_prep(const float4* __restrict__ x, const float4* __restrict__ tok,
                       const int* __restrict__ mflag, const float* __restrict__ dinv_out,
                       half4* __restrict__ Ah4) {
    int i = blockIdx.x * blockDim.x + threadIdx.x; // over N*32 float4s
    if (i < N * 32) {
        int row = i >> 5;
        int c = i & 31;
        float s = dinv_out[row];
        float4 v = mflag[row] ? tok[c] : x[i];
        half4 h;
        h[0] = (_Float16)(v.x * s);
        h[1] = (_Float16)(v.y * s);
        h[2] = (_Float16)(v.z * s);
        h[3] = (_Float16)(v.w * s);
        Ah4[i] = h;
    }
}

// ---------------- SpMM: B[row] = sum over bucket neighbors of Ah[col], fp16 out

__launch_bounds__(256)
__global__ void k_spmm(const half8* __restrict__ Ah8, half8* __restrict__ Bh8,
                       const int* __restrict__ deg, const unsigned short* __restrict__ col) {
    int wv = threadIdx.x >> 6, lane = threadIdx.x & 63;
    int q = lane >> 4, j = lane & 15;
    int row = blockIdx.x * 4 + wv;
    if (row >= N) return;
    int dg = deg[row];
    const unsigned short* crow = col + (size_t)row * CAP;
    float a0 = 0.f, a1 = 0.f, a2 = 0.f, a3 = 0.f;
    float a4 = 0.f, a5 = 0.f, a6 = 0.f, a7 = 0.f;
    int e = q;
    for (; e + 12 < dg; e += 16) {
        int c0 = crow[e], c1 = crow[e + 4], c2 = crow[e + 8], c3 = crow[e + 12];
        half8 h0 = Ah8[(size_t)c0 * 16 + j];
        half8 h1 = Ah8[(size_t)c1 * 16 + j];
        half8 h2 = Ah8[(size_t)c2 * 16 + j];
        half8 h3 = Ah8[(size_t)c3 * 16 + j];
#define SP_ACC4(i) a##i += (float)h0[i]; a##i += (float)h1[i];                 \
                   a##i += (float)h2[i]; a##i += (float)h3[i];
        ROW8(SP_ACC4)
#undef SP_ACC4
    }
    for (; e + 4 < dg; e += 8) {
        int c0 = crow[e], c1 = crow[e + 4];
        half8 h0 = Ah8[(size_t)c0 * 16 + j];
        half8 h1 = Ah8[(size_t)c1 * 16 + j];
#define SP_ACC(i) a##i += (float)h0[i]; a##i += (float)h1[i];
        ROW8(SP_ACC)
#undef SP_ACC
    }
    if (e < dg) {
        int c0 = crow[e];
        half8 h0 = Ah8[(size_t)c0 * 16 + j];
#define SP_ACC1(i) a##i += (float)h0[i];
        ROW8(SP_ACC1)
#undef SP_ACC1
    }
#pragma unroll
    for (int o = 16; o <= 32; o <<= 1) {
#define SP_SHFL(i) a##i += __shfl_xor(a##i, o);
        ROW8(SP_SHFL)
#undef SP_SHFL
    }
    if (q == 0) {
        half8 ho;
#define SP_PACK(i) ho[i] = (_Float16)a##i;
        ROW8(SP_PACK)
#undef SP_PACK
        Bh8[(size_t)row * 16 + j] = ho;
    }
}

// ---------------- MFMA dense: 256 thr, 32 rows x 128 cols, K=128 -------------
// verified layout (R10, absmax 0): A lane row=lane&15 k=quad*8; B = W row-major;
// C col=lane&15, row=quad*4+reg.

template <bool LN, bool SCALE_OUT, bool MASK_ZERO>
__launch_bounds__(256)
__global__ void k_mf(const _Float16* __restrict__ Ain, _Float16* __restrict__ outh,
                     const _Float16* __restrict__ Wh,
                     const float* __restrict__ bias, const float* __restrict__ g,
                     const float* __restrict__ be, const float* __restrict__ aP,
                     const float* __restrict__ dinv_in, const float* __restrict__ dinv_out,
                     const int* __restrict__ mflag) {
    __shared__ float shc[32][132];
    __shared__ float smu[32], srs[32];
    int t = threadIdx.x;
    int w = t >> 6, lane = t & 63;
    int rl = lane & 15, quad = lane >> 4;
    int r0 = blockIdx.x * 32;
    int ra0 = r0 + rl;      if (ra0 > N - 1) ra0 = N - 1;
    int ra1 = r0 + 16 + rl; if (ra1 > N - 1) ra1 = N - 1;
    const half8* A0p = (const half8*)(Ain + (size_t)ra0 * 128 + quad * 8);
    const half8* A1p = (const half8*)(Ain + (size_t)ra1 * 128 + quad * 8);
    const half8* B0p = (const half8*)(Wh + (size_t)(w * 32 + rl) * 128 + quad * 8);
    const half8* B1p = (const half8*)(Wh + (size_t)(w * 32 + 16 + rl) * 128 + quad * 8);
    f32x4 c00 = {0.f, 0.f, 0.f, 0.f}, c01 = c00, c10 = c00, c11 = c00;
#pragma unroll
    for (int kk = 0; kk < 4; ++kk) {
        half8 a0 = A0p[kk * 4];
        half8 a1 = A1p[kk * 4];
        half8 b0 = B0p[kk * 4];
        half8 b1 = B1p[kk * 4];
        c00 = __builtin_amdgcn_mfma_f32_16x16x32_f16(a0, b0, c00, 0, 0, 0);
        c01 = __builtin_amdgcn_mfma_f32_16x16x32_f16(a0, b1, c01, 0, 0, 0);
        c10 = __builtin_amdgcn_mfma_f32_16x16x32_f16(a1, b0, c10, 0, 0, 0);
        c11 = __builtin_amdgcn_mfma_f32_16x16x32_f16(a1, b1, c11, 0, 0, 0);
    }
#pragma unroll
    for (int reg = 0; reg < 4; ++reg) {
        shc[quad * 4 + reg][w * 32 + rl] = c00[reg];
        shc[quad * 4 + reg][w * 32 + 16 + rl] = c01[reg];
        shc[16 + quad * 4 + reg][w * 32 + rl] = c10[reg];
        shc[16 + quad * 4 + reg][w * 32 + 16 + rl] = c11[reg];
    }
    __syncthreads();
    if constexpr (LN) {
        int row = t >> 3, seg = t & 7;
        int rr = r0 + row;
        float di = dinv_in[rr > N - 1 ? N - 1 : rr];
        float s = 0.f, q = 0.f;
#pragma unroll
        for (int c = 0; c < 16; ++c) {
            int cc = seg * 16 + c;
            float v = (shc[row][cc] + bias[cc]) * di;
            s += v;
            q += v * v;
        }
#pragma unroll
        for (int o = 1; o <= 4; o <<= 1) {
            s += __shfl_xor(s, o);
            q += __shfl_xor(q, o);
        }
        if (seg == 0) {
            float mu = s * (1.f / 128.f);
            float var = q * (1.f / 128.f) - mu * mu;
            smu[row] = mu;
            srs[row] = rsqrtf(var + 1e-5f);
        }
        __syncthreads();
    }
    int lane64 = t & 63, grp = t >> 6;
    int cc0 = lane64 * 2, cc1 = cc0 + 1;
    float bt0 = 0.f, bt1 = 0.f, gt0 = 0.f, gt1 = 0.f, be0 = 0.f, be1 = 0.f, alpha = 0.f;
    if constexpr (LN) {
        bt0 = bias[cc0]; bt1 = bias[cc1];
        gt0 = g[cc0]; gt1 = g[cc1];
        be0 = be[cc0]; be1 = be[cc1];
        alpha = aP[0];
    }
#pragma unroll
    for (int i = 0; i < 8; ++i) {
        int lr = grp * 8 + i, r = r0 + lr;
        if (r < N) {
            float v0 = shc[lr][cc0], v1 = shc[lr][cc1];
            if constexpr (LN) {
                float di = dinv_in[r];
                v0 = (v0 + bt0) * di;
                v1 = (v1 + bt1) * di;
                float mu = smu[lr], rs = srs[lr];
                v0 = (v0 - mu) * rs * gt0 + be0;
                v1 = (v1 - mu) * rs * gt1 + be1;
                v0 = v0 >= 0.f ? v0 : alpha * v0;
                v1 = v1 >= 0.f ? v1 : alpha * v1;
            }
            if (MASK_ZERO && mflag[r]) { v0 = 0.f; v1 = 0.f; }
            if constexpr (SCALE_OUT) {
                float so = dinv_out[r];
                v0 *= so; v1 *= so;
            }
            half2v hv;
            hv[0] = (_Float16)v0;
            hv[1] = (_Float16)v1;
            *(half2v*)(outh + (size_t)r * 128 + cc0) = hv;
        }
    }
}

// ---------------- fused conv2-epilogue + encoder_to_decoder (MFMA x2) --------

__launch_bounds__(256)
__global__ void k_mf2(const _Float16* __restrict__ Ain, _Float16* __restrict__ outh,
                      const _Float16* __restrict__ Wh2, const _Float16* __restrict__ WhE,
                      const float* __restrict__ bias, const float* __restrict__ g,
                      const float* __restrict__ be, const float* __restrict__ aP,
                      const float* __restrict__ dinv_in, const float* __restrict__ dinv_out,
                      const int* __restrict__ mflag) {
    __shared__ float shc[32][132];
    __shared__ _Float16 shh[32][136];
    __shared__ float smu[32], srs[32], sdo[32];
    __shared__ int smf[32];
    int t = threadIdx.x;
    int w = t >> 6, lane = t & 63;
    int rl = lane & 15, quad = lane >> 4;
    int r0 = blockIdx.x * 32;
    if (t < 32) {
        int r = r0 + t;
        int rc = r > N - 1 ? N - 1 : r;
        sdo[t] = dinv_out[rc];
        smf[t] = mflag[rc];
    }
    int ra0 = r0 + rl;      if (ra0 > N - 1) ra0 = N - 1;
    int ra1 = r0 + 16 + rl; if (ra1 > N - 1) ra1 = N - 1;
    const half8* A0p = (const half8*)(Ain + (size_t)ra0 * 128 + quad * 8);
    const half8* A1p = (const half8*)(Ain + (size_t)ra1 * 128 + quad * 8);
    const half8* B0p = (const half8*)(Wh2 + (size_t)(w * 32 + rl) * 128 + quad * 8);
    const half8* B1p = (const half8*)(Wh2 + (size_t)(w * 32 + 16 + rl) * 128 + quad * 8);
    f32x4 c00 = {0.f, 0.f, 0.f, 0.f}, c01 = c00, c10 = c00, c11 = c00;
#pragma unroll
    for (int kk = 0; kk < 4; ++kk) {
        half8 a0 = A0p[kk * 4];
        half8 a1 = A1p[kk * 4];
        half8 b0 = B0p[kk * 4];
        half8 b1 = B1p[kk * 4];
        c00 = __builtin_amdgcn_mfma_f32_16x16x32_f16(a0, b0, c00, 0, 0, 0);
        c01 = __builtin_amdgcn_mfma_f32_16x16x32_f16(a0, b1, c01, 0, 0, 0);
        c10 = __builtin_amdgcn_mfma_f32_16x16x32_f16(a1, b0, c10, 0, 0, 0);
        c11 = __builtin_amdgcn_mfma_f32_16x16x32_f16(a1, b1, c11, 0, 0, 0);
    }
#pragma unroll
    for (int reg = 0; reg < 4; ++reg) {
        shc[quad * 4 + reg][w * 32 + rl] = c00[reg];
        shc[quad * 4 + reg][w * 32 + 16 + rl] = c01[reg];
        shc[16 + quad * 4 + reg][w * 32 + rl] = c10[reg];
        shc[16 + quad * 4 + reg][w * 32 + 16 + rl] = c11[reg];
    }
    __syncthreads();
    { // LN stats
        int row = t >> 3, seg = t & 7;
        int rr = r0 + row;
        float di = dinv_in[rr > N - 1 ? N - 1 : rr];
        float s = 0.f, q = 0.f;
#pragma unroll
        for (int c = 0; c < 16; ++c) {
            int cc = seg * 16 + c;
            float v = (shc[row][cc] + bias[cc]) * di;
            s += v;
            q += v * v;
        }
#pragma unroll
        for (int o = 1; o <= 4; o <<= 1) {
            s += __shfl_xor(s, o);
            q += __shfl_xor(q, o);
        }
        if (seg == 0) {
            float mu = s * (1.f / 128.f);
            float var = q * (1.f / 128.f) - mu * mu;
            smu[row] = mu;
            srs[row] = rsqrtf(var + 1e-5f);
        }
        __syncthreads();
    }
    { // h2 -> shh (fp16)
        int lane64 = t & 63, grp = t >> 6;
        int cc0 = lane64 * 2, cc1 = cc0 + 1;
        float bt0 = bias[cc0], bt1 = bias[cc1];
        float gt0 = g[cc0], gt1 = g[cc1];
        float be0 = be[cc0], be1 = be[cc1];
        float alpha = aP[0];
#pragma unroll
        for (int i = 0; i < 8; ++i) {
            int lr = grp * 8 + i, r = r0 + lr;
            float v0 = 0.f, v1 = 0.f;
            if (r < N) {
                float di = dinv_in[r];
                v0 = (shc[lr][cc0] + bt0) * di;
                v1 = (shc[lr][cc1] + bt1) * di;
                float mu = smu[lr], rs = srs[lr];
                v0 = (v0 - mu) * rs * gt0 + be0;
                v1 = (v1 - mu) * rs * gt1 + be1;
                v0 = v0 >= 0.f ? v0 : alpha * v0;
                v1 = v1 >= 0.f ? v1 : alpha * v1;
            }
            shh[lr][cc0] = (_Float16)v0;
            shh[lr][cc1] = (_Float16)v1;
        }
    }
    __syncthreads();
    const half8* E0p = (const half8*)(WhE + (size_t)(w * 32 + rl) * 128 + quad * 8);
    const half8* E1p = (const half8*)(WhE + (size_t)(w * 32 + 16 + rl) * 128 + quad * 8);
    f32x4 d00 = {0.f, 0.f, 0.f, 0.f}, d01 = d00, d10 = d00, d11 = d00;
#pragma unroll
    for (int kk = 0; kk < 4; ++kk) {
        half8 a0 = *(const half8*)&shh[rl][kk * 32 + quad * 8];
        half8 a1 = *(const half8*)&shh[16 + rl][kk * 32 + quad * 8];
        half8 b0 = E0p[kk * 4];
        half8 b1 = E1p[kk * 4];
        d00 = __builtin_amdgcn_mfma_f32_16x16x32_f16(a0, b0, d00, 0, 0, 0);
        d01 = __builtin_amdgcn_mfma_f32_16x16x32_f16(a0, b1, d01, 0, 0, 0);
        d10 = __builtin_amdgcn_mfma_f32_16x16x32_f16(a1, b0, d10, 0, 0, 0);
        d11 = __builtin_amdgcn_mfma_f32_16x16x32_f16(a1, b1, d11, 0, 0, 0);
    }
#pragma unroll
    for (int reg = 0; reg < 4; ++reg) {
        int lr = quad * 4 + reg, r = r0 + lr;
        if (r < N) {
            float s = smf[lr] ? 0.f : sdo[lr];
            outh[(size_t)r * 128 + w * 32 + rl] = (_Float16)(d00[reg] * s);
            outh[(size_t)r * 128 + w * 32 + 16 + rl] = (_Float16)(d01[reg] * s);
        }
        int lr2 = 16 + lr, r2 = r0 + lr2;
        if (r2 < N) {
            float s = smf[lr2] ? 0.f : sdo[lr2];
            outh[(size_t)r2 * 128 + w * 32 + rl] = (_Float16)(d10[reg] * s);
            outh[(size_t)r2 * 128 + w * 32 + 16 + rl] = (_Float16)(d11[reg] * s);
        }
    }
}

// ---------------- fused conv3-SpMM + decoder fc + SCE loss -------------------
// phase 1: gather-SpMM for 32 masked rows -> fp16 LDS; phase 2: MFMA + loss.

__launch_bounds__(256)
__global__ void k_spmf_loss(const half8* __restrict__ Ah8, const float* __restrict__ x,
                            const _Float16* __restrict__ Wh, const float* __restrict__ bd,
                            const int* __restrict__ deg, const unsigned short* __restrict__ col,
                            const float* __restrict__ dinv_in,
                            const int* __restrict__ mask_nodes, float* __restrict__ outp) {
    __shared__ float shc[32][132];
    __shared__ _Float16 shh[32][136];
    __shared__ int shm[32];
    __shared__ float sterm[32];
    int t = threadIdx.x;
    int w = t >> 6, lane = t & 63;
    int rl = lane & 15, quad = lane >> 4;
    int q = lane >> 4, j = lane & 15;
    int i0 = blockIdx.x * 32;
    if (t < 32) {
        int idx = i0 + t;
        shm[t] = idx < MASKN ? mask_nodes[idx] : -1;
    }
    __syncthreads();
    // phase 1: SpMM, wave w handles tile rows w*8 .. w*8+7
    for (int rr = 0; rr < 8; ++rr) {
        int lr = w * 8 + rr;
        int m = shm[lr];
        float a0 = 0.f, a1 = 0.f, a2 = 0.f, a3 = 0.f;
        float a4 = 0.f, a5 = 0.f, a6 = 0.f, a7 = 0.f;
        if (m >= 0) {
            int dg = deg[m];
            const unsigned short* crow = col + (size_t)m * CAP;
            int e = q;
            for (; e + 12 < dg; e += 16) {
                int c0 = crow[e], c1 = crow[e + 4], c2 = crow[e + 8], c3 = crow[e + 12];
                half8 h0 = Ah8[(size_t)c0 * 16 + j];
                half8 h1 = Ah8[(size_t)c1 * 16 + j];
                half8 h2 = Ah8[(size_t)c2 * 16 + j];
                half8 h3 = Ah8[(size_t)c3 * 16 + j];
#define SP_ACC4(i) a##i += (float)h0[i]; a##i += (float)h1[i];                 \
                   a##i += (float)h2[i]; a##i += (float)h3[i];
                ROW8(SP_ACC4)
#undef SP_ACC4
            }
            for (; e + 4 < dg; e += 8) {
                int c0 = crow[e], c1 = crow[e + 4];
                half8 h0 = Ah8[(size_t)c0 * 16 + j];
                half8 h1 = Ah8[(size_t)c1 * 16 + j];
#define SP_ACC(i) a##i += (float)h0[i]; a##i += (float)h1[i];
                ROW8(SP_ACC)
#undef SP_ACC
            }
            if (e < dg) {
                int c0 = crow[e];
                half8 h0 = Ah8[(size_t)c0 * 16 + j];
#define SP_ACC1(i) a##i += (float)h0[i];
                ROW8(SP_ACC1)
#undef SP_ACC1
            }
        }
#pragma unroll
        for (int o = 16; o <= 32; o <<= 1) {
#define SP_SHFL(i) a##i += __shfl_xor(a##i, o);
            ROW8(SP_SHFL)
#undef SP_SHFL
        }
        if (q == 0) {
            half8 ho;
#define SP_PACK(i) ho[i] = (_Float16)a##i;
            ROW8(SP_PACK)
#undef SP_PACK
            *(half8*)&shh[lr][j * 8] = ho;
        }
    }
    __syncthreads();
    // phase 2: MFMA vs WhD
    const half8* B0p = (const half8*)(Wh + (size_t)(w * 32 + rl) * 128 + quad * 8);
    const half8* B1p = (const half8*)(Wh + (size_t)(w * 32 + 16 + rl) * 128 + quad * 8);
    f32x4 c00 = {0.f, 0.f, 0.f, 0.f}, c01 = c00, c10 = c00, c11 = c00;
#pragma unroll
    for (int kk = 0; kk < 4; ++kk) {
        half8 a0 = *(const half8*)&shh[rl][kk * 32 + quad * 8];
        half8 a1 = *(const half8*)&shh[16 + rl][kk * 32 + quad * 8];
        half8 b0 = B0p[kk * 4];
        half8 b1 = B1p[kk * 4];
        c00 = __builtin_amdgcn_mfma_f32_16x16x32_f16(a0, b0, c00, 0, 0, 0);
        c01 = __builtin_amdgcn_mfma_f32_16x16x32_f16(a0, b1, c01, 0, 0, 0);
        c10 = __builtin_amdgcn_mfma_f32_16x16x32_f16(a1, b0, c10, 0, 0, 0);
        c11 = __builtin_amdgcn_mfma_f32_16x16x32_f16(a1, b1, c11, 0, 0, 0);
    }
#pragma unroll
    for (int reg = 0; reg < 4; ++reg) {
        shc[quad * 4 + reg][w * 32 + rl] = c00[reg];
        shc[quad * 4 + reg][w * 32 + 16 + rl] = c01[reg];
        shc[16 + quad * 4 + reg][w * 32 + rl] = c10[reg];
        shc[16 + quad * 4 + reg][w * 32 + 16 + rl] = c11[reg];
    }
    __syncthreads();
    int row = t >> 3, seg = t & 7;
    int m = shm[row];
    float a = 0.f, b = 0.f, c = 0.f;
    if (m >= 0) {
        float di = dinv_in[m];
#pragma unroll
        for (int cc0 = 0; cc0 < 16; ++cc0) {
            int cc = seg * 16 + cc0;
            float r = (shc[row][cc] + bd[cc]) * di;
            float xv = x[(size_t)m * 128 + cc];
            a += r * r;
            b += xv * xv;
            c += r * xv;
        }
    }
#pragma unroll
    for (int o = 1; o <= 4; o <<= 1) {
        a += __shfl_xor(a, o);
        b += __shfl_xor(b, o);
        c += __shfl_xor(c, o);
    }
    if (seg == 0) {
        float term = 0.f;
        if (m >= 0) {
            float nr = fmaxf(sqrtf(a), 1e-12f);
            float nx = fmaxf(sqrtf(b), 1e-12f);
            float d = 1.f - c / (nr * nx);
            term = d * d;
        }
        sterm[row] = term;
    }
    __syncthreads();
    if (t == 0) {
        float sum = 0.f;
#pragma unroll
        for (int i = 0; i < 32; ++i) sum += sterm[i];
        atomicAdd(outp, sum * (1.f / MASKN));
    }
}

// ---------------- launch ----------------

extern "C" void kernel_launch(void* const* d_in, const int* in_sizes, int n_in,
                              void* d_out, int out_size, void* d_ws, size_t ws_size,
                              hipStream_t stream) {
    const float* x = (const float*)d_in[0];
    const float* tok = (const float*)d_in[1];
    const float* W1 = (const float*)d_in[2];
    const float* b1 = (const float*)d_in[3];
    const float* g1 = (const float*)d_in[4];
    const float* be1 = (const float*)d_in[5];
    const float* a1 = (const float*)d_in[6];
    const float* W2 = (const float*)d_in[7];
    const float* b2 = (const float*)d_in[8];
    const float* g2 = (const float*)d_in[9];
    const float* be2 = (const float*)d_in[10];
    const float* a2 = (const float*)d_in[11];
    const float* We2d = (const float*)d_in[12];
    const float* Wd = (const float*)d_in[13];
    const float* bd = (const float*)d_in[14];
    const int* src = (const int*)d_in[15];
    const int* dst = (const int*)d_in[16];
    const int* mask_nodes = (const int*)d_in[17];

    char* w = (char*)d_ws;
    _Float16* Ah = (_Float16*)w;        w += (size_t)N * D * 2;
    _Float16* Bh = (_Float16*)w;        w += (size_t)N * D * 2;
    unsigned short* col = (unsigned short*)w; w += (size_t)N * CAP * 2;
    int* cursor = (int*)w;              w += (size_t)N * 4; // becomes deg_in
    int* mflag = (int*)w;               w += (size_t)N * 4;
    float* dinv_out = (float*)w;        w += (size_t)N * 4;
    float* dinv_in = (float*)w;         w += (size_t)N * 4;
    _Float16* Wh1 = (_Float16*)w;       w += (size_t)D * D * 2;
    _Float16* Wh2 = (_Float16*)w;       w += (size_t)D * D * 2;
    _Float16* WhE = (_Float16*)w;       w += (size_t)D * D * 2;
    _Float16* WhD = (_Float16*)w;       w += (size_t)D * D * 2;
    unsigned int* partial = (unsigned int*)w; w += (size_t)HB * HW * 4;

    // zero cursor, mflag (contiguous 2*N ints) + output scalar
    hipMemsetAsync(cursor, 0, (size_t)2 * N * 4, stream);
    hipMemsetAsync(d_out, 0, sizeof(float), stream);

    k_build<<<(E + 255) / 256, 256, 0, stream>>>(src, dst, cursor, col);
    k_hist<<<HB, 256, 0, stream>>>(src, partial);
    k_misc<<<310, 256, 0, stream>>>(W1, W2, We2d, Wd, Wh1, Wh2, WhE, WhD,
                                    partial, cursor, dinv_out, dinv_in, mask_nodes, mflag);
    k_prep<<<(N * 32 + 255) / 256, 256, 0, stream>>>((const float4*)x, (const float4*)tok,
                                                     mflag, dinv_out, (half4*)Ah);
    int nmf = (N + 31) / 32;        // 1563
    int nmfl = (MASKN + 31) / 32;   // 782
    int nspmm = (N + 3) / 4;
    // conv1: agg (fp16 gather, fp16 out)
    k_spmm<<<nspmm, 256, 0, stream>>>((const half8*)Ah, (half8*)Bh, cursor, col);
    // conv1 epilogue (MFMA): fc + in-deg norm + LN + PReLU, pre-scale deg_out^-0.5
    k_mf<true, true, false><<<nmf, 256, 0, stream>>>(
        Bh, Ah, Wh1, b1, g1, be1, a1, dinv_in, dinv_out, nullptr);
    // conv2: agg
    k_spmm<<<nspmm, 256, 0, stream>>>((const half8*)Ah, (half8*)Bh, cursor, col);
    // conv2 epilogue + encoder_to_decoder + re-mask + pre-scale (fused, MFMA x2)
    k_mf2<<<nmf, 256, 0, stream>>>(
        Bh, Ah, Wh2, WhE, b2, g2, be2, a2, dinv_in, dinv_out, mflag);
    // conv3 agg + decoder fc + SCE loss (fused)
    k_spmf_loss<<<nmfl, 256, 0, stream>>>((const half8*)Ah, x, WhD, bd, cursor, col,
                                          dinv_in, mask_nodes, (float*)d_out);
}